// Round 1
// baseline (896.052 us; speedup 1.0000x reference)
//
#include <hip/hip_runtime.h>
#include <math.h>

// Problem dims (fixed by the reference)
constexpr int NB  = 16;    // batch
constexpr int NP  = 1024;  // prev points
constexpr int NS  = 4096;  // skip points
constexpr int CP  = 256;   // prev channels
constexpr int CS  = 128;   // skip channels
constexpr int CIN = 384;   // CP + CS
constexpr int CO  = 256;   // output channels

__device__ __forceinline__ void ins3(float d, int i,
                                     float& d0, int& i0,
                                     float& d1, int& i1,
                                     float& d2, int& i2) {
  // tie-break: lower index wins (matches jax.lax.top_k stability)
  bool b2 = (d < d2) || (d == d2 && i < i2);
  if (!b2) return;
  bool b1 = (d < d1) || (d == d1 && i < i1);
  if (!b1) { d2 = d; i2 = i; return; }
  d2 = d1; i2 = i1;
  bool b0 = (d < d0) || (d == d0 && i < i0);
  if (!b0) { d1 = d; i1 = i; return; }
  d1 = d0; i1 = i0; d0 = d; i0 = i;
}

// One wave per skip point: top-3 nearest prev points + sum of reciprocal dists.
__global__ __launch_bounds__(256) void topk_kernel(
    const float* __restrict__ xyz_prev, const float* __restrict__ xyz_skip,
    float* __restrict__ w3, int* __restrict__ idx3) {
  __shared__ float px[NP], py[NP], pz[NP];
  int bidx = blockIdx.x;           // NB*NS/4 blocks
  int b = bidx >> 10;              // NS/4 = 1024 blocks per batch
  int nblk = bidx & 1023;
  const float* xp = xyz_prev + (size_t)b * NP * 3;
  for (int i = threadIdx.x; i < NP; i += 256) {
    px[i] = xp[i * 3 + 0]; py[i] = xp[i * 3 + 1]; pz[i] = xp[i * 3 + 2];
  }
  __syncthreads();
  int wave = threadIdx.x >> 6, lane = threadIdx.x & 63;
  int n = nblk * 4 + wave;
  const float* q = xyz_skip + ((size_t)b * NS + n) * 3;
  float qx = q[0], qy = q[1], qz = q[2];
  float rsum = 0.f;
  float d0 = INFINITY, d1 = INFINITY, d2 = INFINITY;
  int i0 = 0x7fffffff, i1 = 0x7fffffff, i2 = 0x7fffffff;
  for (int p = lane; p < NP; p += 64) {
    float dx = px[p] - qx, dy = py[p] - qy, dz = pz[p] - qz;
    float dd = sqrtf(dx * dx + dy * dy + dz * dz);
    rsum += 1.0f / (dd + 1e-8f);
    ins3(dd, p, d0, i0, d1, i1, d2, i2);
  }
  #pragma unroll
  for (int m = 1; m < 64; m <<= 1) {
    rsum += __shfl_xor(rsum, m);
    float od0 = __shfl_xor(d0, m), od1 = __shfl_xor(d1, m), od2 = __shfl_xor(d2, m);
    int   oi0 = __shfl_xor(i0, m), oi1 = __shfl_xor(i1, m), oi2 = __shfl_xor(i2, m);
    ins3(od0, oi0, d0, i0, d1, i1, d2, i2);
    ins3(od1, oi1, d0, i0, d1, i1, d2, i2);
    ins3(od2, oi2, d0, i0, d1, i1, d2, i2);
  }
  if (lane == 0) {
    size_t base = ((size_t)b * NS + n) * 3;
    float inv = 1.0f / rsum;
    w3[base + 0] = (1.0f / (d0 + 1e-8f)) * inv;
    w3[base + 1] = (1.0f / (d1 + 1e-8f)) * inv;
    w3[base + 2] = (1.0f / (d2 + 1e-8f)) * inv;
    idx3[base + 0] = i0; idx3[base + 1] = i1; idx3[base + 2] = i2;
  }
}

// GEMM1: y1[o][n] = sum_c W1[o][c] * x[c][n], x = [interp(256); skip(128)].
// Writes y1 transposed: y1T[b][n][o]. Accumulates BN stats per channel o.
__global__ __launch_bounds__(256) void gemm1_kernel(
    const float* __restrict__ points_prev, const float* __restrict__ points_skip,
    const float* __restrict__ W1, const float* __restrict__ w3,
    const int* __restrict__ idx3, float* __restrict__ y1T,
    float* __restrict__ stats1) {
  __shared__ float Ws[16][CO];
  __shared__ float xs[16][68];
  __shared__ float w3s[64][3];
  __shared__ int   idx3s[64][3];
  __shared__ float ssum[CO], ssq[CO];
  int tid = threadIdx.x;
  int n0 = blockIdx.x * 64;
  int b = blockIdx.y;
  if (tid < 192) {
    size_t base = ((size_t)b * NS + n0) * 3;
    w3s[tid / 3][tid % 3] = w3[base + tid];
    idx3s[tid / 3][tid % 3] = idx3[base + tid];
  }
  ssum[tid] = 0.f; ssq[tid] = 0.f;
  __syncthreads();
  const float* PP = points_prev + (size_t)b * CP * NP;
  const float* PS = points_skip + (size_t)b * CS * NS;
  float acc[8][8];
  #pragma unroll
  for (int m = 0; m < 8; m++)
    #pragma unroll
    for (int i = 0; i < 8; i++) acc[m][i] = 0.f;
  int tx = tid & 31, ty = tid >> 5;
  for (int kc = 0; kc < CIN; kc += 16) {
    { // load W tile [16 c][256 o] — quads of threads read float4 along c
      int qd = tid & 3, orow = tid >> 2;
      #pragma unroll
      for (int r = 0; r < 4; r++) {
        int o = r * 64 + orow;
        const float4 v = *(const float4*)(W1 + (size_t)o * CIN + kc + qd * 4);
        Ws[qd * 4 + 0][o] = v.x; Ws[qd * 4 + 1][o] = v.y;
        Ws[qd * 4 + 2][o] = v.z; Ws[qd * 4 + 3][o] = v.w;
      }
    }
    { // load x tile [16 c][64 n] on the fly
      int k = tid & 15, nl = (tid >> 4) * 4, c = kc + k;
      if (c < CP) {
        const float* row = PP + (size_t)c * NP;
        #pragma unroll
        for (int q2 = 0; q2 < 4; q2++) {
          int nn = nl + q2;
          float v = w3s[nn][0] * row[idx3s[nn][0]]
                  + w3s[nn][1] * row[idx3s[nn][1]]
                  + w3s[nn][2] * row[idx3s[nn][2]];
          xs[k][nn] = v;
        }
      } else {
        const float4 v = *(const float4*)(PS + (size_t)(c - CP) * NS + n0 + nl);
        xs[k][nl] = v.x; xs[k][nl + 1] = v.y; xs[k][nl + 2] = v.z; xs[k][nl + 3] = v.w;
      }
    }
    __syncthreads();
    #pragma unroll
    for (int k = 0; k < 16; k++) {
      float wr[8], xr[8];
      #pragma unroll
      for (int m = 0; m < 8; m++) wr[m] = Ws[k][tx + 32 * m];
      #pragma unroll
      for (int i = 0; i < 8; i++) xr[i] = xs[k][ty * 8 + i];
      #pragma unroll
      for (int m = 0; m < 8; m++)
        #pragma unroll
        for (int i = 0; i < 8; i++) acc[m][i] = fmaf(wr[m], xr[i], acc[m][i]);
    }
    __syncthreads();
  }
  #pragma unroll
  for (int m = 0; m < 8; m++) {
    float ps = 0.f, pq = 0.f;
    #pragma unroll
    for (int i = 0; i < 8; i++) { float v = acc[m][i]; ps += v; pq += v * v; }
    atomicAdd(&ssum[tx + 32 * m], ps);
    atomicAdd(&ssq[tx + 32 * m], pq);
  }
  float* Y = y1T + (size_t)b * NS * CO;
  #pragma unroll
  for (int i = 0; i < 8; i++) {
    int n = n0 + ty * 8 + i;
    float* yr = Y + (size_t)n * CO + tx;
    #pragma unroll
    for (int m = 0; m < 8; m++) yr[32 * m] = acc[m][i];
  }
  __syncthreads();
  atomicAdd(&stats1[tid], ssum[tid]);
  atomicAdd(&stats1[CO + tid], ssq[tid]);
}

// stats -> per-channel affine: z = a*y + s, then relu
__global__ void bnstats_kernel(const float* __restrict__ stats,
                               const float* __restrict__ g,
                               const float* __restrict__ bt,
                               float* __restrict__ a, float* __restrict__ s) {
  int o = threadIdx.x;
  float cnt = (float)NB * (float)NS;
  float m = stats[o] / cnt;
  float var = stats[CO + o] / cnt - m * m;
  var = fmaxf(var, 0.f);
  float inv = rsqrtf(var + 1e-5f);
  float av = g[o] * inv;
  a[o] = av; s[o] = bt[o] - m * av;
}

// GEMM2: y2[o][n] = sum_c W2[o][c] * relu(a1[c]*y1[c][n]+s1[c]); y2 transposed out.
__global__ __launch_bounds__(256) void gemm2_kernel(
    const float* __restrict__ y1T, const float* __restrict__ W2,
    const float* __restrict__ a1, const float* __restrict__ s1,
    float* __restrict__ y2T, float* __restrict__ stats2) {
  __shared__ float Ws[16][CO];
  __shared__ float xs[16][68];
  __shared__ float ssum[CO], ssq[CO];
  int tid = threadIdx.x;
  int n0 = blockIdx.x * 64;
  int b = blockIdx.y;
  ssum[tid] = 0.f; ssq[tid] = 0.f;
  __syncthreads();
  const float* Y1 = y1T + (size_t)b * NS * CO;
  float acc[8][8];
  #pragma unroll
  for (int m = 0; m < 8; m++)
    #pragma unroll
    for (int i = 0; i < 8; i++) acc[m][i] = 0.f;
  int tx = tid & 31, ty = tid >> 5;
  for (int kc = 0; kc < CO; kc += 16) {
    {
      int qd = tid & 3, orow = tid >> 2;
      #pragma unroll
      for (int r = 0; r < 4; r++) {
        int o = r * 64 + orow;
        const float4 v = *(const float4*)(W2 + (size_t)o * CO + kc + qd * 4);
        Ws[qd * 4 + 0][o] = v.x; Ws[qd * 4 + 1][o] = v.y;
        Ws[qd * 4 + 2][o] = v.z; Ws[qd * 4 + 3][o] = v.w;
      }
    }
    {
      int k = tid & 15, nl = (tid >> 4) * 4, c = kc + k;
      float ac = a1[c], sc = s1[c];
      #pragma unroll
      for (int q2 = 0; q2 < 4; q2++) {
        float v = Y1[(size_t)(n0 + nl + q2) * CO + c];
        xs[k][nl + q2] = fmaxf(fmaf(ac, v, sc), 0.f);
      }
    }
    __syncthreads();
    #pragma unroll
    for (int k = 0; k < 16; k++) {
      float wr[8], xr[8];
      #pragma unroll
      for (int m = 0; m < 8; m++) wr[m] = Ws[k][tx + 32 * m];
      #pragma unroll
      for (int i = 0; i < 8; i++) xr[i] = xs[k][ty * 8 + i];
      #pragma unroll
      for (int m = 0; m < 8; m++)
        #pragma unroll
        for (int i = 0; i < 8; i++) acc[m][i] = fmaf(wr[m], xr[i], acc[m][i]);
    }
    __syncthreads();
  }
  #pragma unroll
  for (int m = 0; m < 8; m++) {
    float ps = 0.f, pq = 0.f;
    #pragma unroll
    for (int i = 0; i < 8; i++) { float v = acc[m][i]; ps += v; pq += v * v; }
    atomicAdd(&ssum[tx + 32 * m], ps);
    atomicAdd(&ssq[tx + 32 * m], pq);
  }
  float* Y = y2T + (size_t)b * NS * CO;
  #pragma unroll
  for (int i = 0; i < 8; i++) {
    int n = n0 + ty * 8 + i;
    float* yr = Y + (size_t)n * CO + tx;
    #pragma unroll
    for (int m = 0; m < 8; m++) yr[32 * m] = acc[m][i];
  }
  __syncthreads();
  atomicAdd(&stats2[tid], ssum[tid]);
  atomicAdd(&stats2[CO + tid], ssq[tid]);
}

// Final BN2+ReLU with transpose [b][n][o] -> [b][o][n] via LDS tile.
__global__ __launch_bounds__(256) void bnrelu_tr_kernel(
    const float* __restrict__ y2T, const float* __restrict__ a2,
    const float* __restrict__ s2, float* __restrict__ out) {
  __shared__ float tl[64][65];
  int n0 = blockIdx.x * 64, o0 = blockIdx.y * 64, b = blockIdx.z;
  const float* Y = y2T + (size_t)b * NS * CO;
  int tid = threadIdx.x;
  int j4 = (tid & 15) * 4, i = tid >> 4;
  #pragma unroll
  for (int r = 0; r < 4; r++) {
    int ii = i + 16 * r;
    float4 v = *(const float4*)(Y + (size_t)(n0 + ii) * CO + o0 + j4);
    tl[ii][j4] = v.x; tl[ii][j4 + 1] = v.y; tl[ii][j4 + 2] = v.z; tl[ii][j4 + 3] = v.w;
  }
  __syncthreads();
  float* O = out + (size_t)b * CO * NS;
  int ii4 = (tid & 15) * 4, j = tid >> 4;
  #pragma unroll
  for (int r = 0; r < 4; r++) {
    int jj = j + 16 * r;
    float av = a2[o0 + jj], sv = s2[o0 + jj];
    float4 v;
    v.x = fmaxf(fmaf(av, tl[ii4 + 0][jj], sv), 0.f);
    v.y = fmaxf(fmaf(av, tl[ii4 + 1][jj], sv), 0.f);
    v.z = fmaxf(fmaf(av, tl[ii4 + 2][jj], sv), 0.f);
    v.w = fmaxf(fmaf(av, tl[ii4 + 3][jj], sv), 0.f);
    *(float4*)(O + (size_t)(o0 + jj) * NS + n0 + ii4) = v;
  }
}

__global__ void zero_kernel(float* st1, float* st2) {
  int t = threadIdx.x;
  if (t < 512) { st1[t] = 0.f; st2[t] = 0.f; }
}

extern "C" void kernel_launch(void* const* d_in, const int* in_sizes, int n_in,
                              void* d_out, int out_size, void* d_ws, size_t ws_size,
                              hipStream_t stream) {
  const float* xyz_prev    = (const float*)d_in[0];
  const float* xyz_skip    = (const float*)d_in[1];
  const float* points_prev = (const float*)d_in[2];
  const float* points_skip = (const float*)d_in[3];
  const float* W1 = (const float*)d_in[4];
  const float* g1 = (const float*)d_in[5];
  const float* b1 = (const float*)d_in[6];
  const float* W2 = (const float*)d_in[7];
  const float* g2 = (const float*)d_in[8];
  const float* b2 = (const float*)d_in[9];
  float* out = (float*)d_out;

  const size_t ybuf = (size_t)NB * NS * CO;           // 16.78M floats
  const size_t full_need = (2 * ybuf + 2 * (size_t)NB * NS * 3 + 4096) * 4;

  float* y1T = (float*)d_ws;
  float* y2T;
  float* tail;
  bool compact = (ws_size < full_need);
  if (!compact) {
    y2T = y1T + ybuf;
    tail = y2T + ybuf;
  } else {
    y2T = out;          // y2 (transposed layout) lives in d_out
    tail = y1T + ybuf;
  }
  float* w3 = tail;
  int* idx3 = (int*)(w3 + (size_t)NB * NS * 3);
  float* st1 = (float*)(idx3 + (size_t)NB * NS * 3);
  float* st2 = st1 + 512;
  float* a1 = st2 + 512; float* s1 = a1 + CO;
  float* a2 = s1 + CO;   float* s2 = a2 + CO;

  hipLaunchKernelGGL(zero_kernel, dim3(1), dim3(512), 0, stream, st1, st2);
  hipLaunchKernelGGL(topk_kernel, dim3(NB * NS / 4), dim3(256), 0, stream,
                     xyz_prev, xyz_skip, w3, idx3);
  hipLaunchKernelGGL(gemm1_kernel, dim3(NS / 64, NB), dim3(256), 0, stream,
                     points_prev, points_skip, W1, w3, idx3, y1T, st1);
  hipLaunchKernelGGL(bnstats_kernel, dim3(1), dim3(256), 0, stream, st1, g1, b1, a1, s1);
  hipLaunchKernelGGL(gemm2_kernel, dim3(NS / 64, NB), dim3(256), 0, stream,
                     y1T, W2, a1, s1, y2T, st2);
  hipLaunchKernelGGL(bnstats_kernel, dim3(1), dim3(256), 0, stream, st2, g2, b2, a2, s2);
  if (!compact) {
    hipLaunchKernelGGL(bnrelu_tr_kernel, dim3(NS / 64, CO / 64, NB), dim3(256), 0, stream,
                       y2T, a2, s2, out);
  } else {
    // y2T == d_out; write final into ws (y1T region, now dead), then copy back
    hipLaunchKernelGGL(bnrelu_tr_kernel, dim3(NS / 64, CO / 64, NB), dim3(256), 0, stream,
                       y2T, a2, s2, y1T);
    hipMemcpyAsync(out, y1T, ybuf * 4, hipMemcpyDeviceToDevice, stream);
  }
}

// Round 2
// 459.543 us; speedup vs baseline: 1.9499x; 1.9499x over previous
//
#include <hip/hip_runtime.h>
#include <math.h>

// Problem dims (fixed by the reference)
constexpr int NB  = 16;    // batch
constexpr int NP  = 1024;  // prev points
constexpr int NS  = 4096;  // skip points
constexpr int CP  = 256;   // prev channels
constexpr int CS  = 128;   // skip channels
constexpr int CIN = 384;   // CP + CS
constexpr int CO  = 256;   // output channels

constexpr int NCHUNK = 8;           // prev-point chunks for topk parallelism
constexpr int CHPTS  = NP / NCHUNK; // 128

// ---------------------------------------------------------------------------
// topk stage 1: per (skip point, chunk) partial top-3 (squared dists) + partial
// sum of reciprocal distances. Branchless insertion (v_cndmask), no sqrt/div.
// 1/(d+1e-8) approximated by rsqrt(d^2+1e-16): same d->0 cap (1e8), <1e-8 rel
// error at typical d. grid = (NS/256, NCHUNK, NB), block = 256.
__global__ __launch_bounds__(256) void topk_chunk_kernel(
    const float* __restrict__ xyz_prev, const float* __restrict__ xyz_skip,
    float* __restrict__ pbuf) {
  __shared__ float px[CHPTS], py[CHPTS], pz[CHPTS];
  int ng = blockIdx.x;
  int q  = blockIdx.y;
  int b  = blockIdx.z;
  int tid = threadIdx.x;
  if (tid < CHPTS) {
    const float* xp = xyz_prev + ((size_t)b * NP + q * CHPTS + tid) * 3;
    px[tid] = xp[0]; py[tid] = xp[1]; pz[tid] = xp[2];
  }
  __syncthreads();
  int n = ng * 256 + tid;
  const float* xq = xyz_skip + ((size_t)b * NS + n) * 3;
  float qx = xq[0], qy = xq[1], qz = xq[2];
  float d0 = INFINITY, d1 = INFINITY, d2 = INFINITY;
  int i0 = -1, i1 = -1, i2 = -1;
  float rsum = 0.f;
  int pbase = q * CHPTS;
  #pragma unroll 8
  for (int p = 0; p < CHPTS; p++) {
    float dx = px[p] - qx, dy = py[p] - qy, dz = pz[p] - qz;
    float sq = fmaf(dz, dz, fmaf(dy, dy, dx * dx));
    rsum += rsqrtf(sq + 1e-16f);
    bool c0 = sq < d0, c1 = sq < d1, c2 = sq < d2;
    int pi = pbase + p;
    d2 = c2 ? (c1 ? d1 : sq) : d2;
    i2 = c2 ? (c1 ? i1 : pi) : i2;
    d1 = c1 ? (c0 ? d0 : sq) : d1;
    i1 = c1 ? (c0 ? i0 : pi) : i1;
    d0 = c0 ? sq : d0;
    i0 = c0 ? pi : i0;
  }
  size_t P = ((size_t)(b * NCHUNK + q) * NS + n) * 8;
  float4 v0 = make_float4(d0, d1, d2, rsum);
  float4 v1;
  v1.x = __int_as_float(i0); v1.y = __int_as_float(i1);
  v1.z = __int_as_float(i2); v1.w = 0.f;
  *(float4*)(pbuf + P) = v0;
  *(float4*)(pbuf + P + 4) = v1;
}

// topk stage 2: merge NCHUNK partials per point, emit normalized 3-NN weights.
// grid = NB*NS/256, block = 256.
__global__ __launch_bounds__(256) void topk_merge_kernel(
    const float* __restrict__ pbuf, float* __restrict__ w3,
    int* __restrict__ idx3) {
  int gid = blockIdx.x * 256 + threadIdx.x;  // = b*NS + n
  int b = gid >> 12;                         // NS = 4096
  int n = gid & (NS - 1);
  float d0 = INFINITY, d1 = INFINITY, d2 = INFINITY;
  int i0 = -1, i1 = -1, i2 = -1;
  float rsum = 0.f;
  for (int q = 0; q < NCHUNK; q++) {
    size_t P = ((size_t)(b * NCHUNK + q) * NS + n) * 8;
    float4 v0 = *(const float4*)(pbuf + P);
    float4 v1 = *(const float4*)(pbuf + P + 4);
    rsum += v0.w;
    float ds[3] = {v0.x, v0.y, v0.z};
    int   is[3] = {__float_as_int(v1.x), __float_as_int(v1.y),
                   __float_as_int(v1.z)};
    #pragma unroll
    for (int k = 0; k < 3; k++) {
      float sq = ds[k]; int pi = is[k];
      bool c0 = sq < d0, c1 = sq < d1, c2 = sq < d2;
      d2 = c2 ? (c1 ? d1 : sq) : d2;
      i2 = c2 ? (c1 ? i1 : pi) : i2;
      d1 = c1 ? (c0 ? d0 : sq) : d1;
      i1 = c1 ? (c0 ? i0 : pi) : i1;
      d0 = c0 ? sq : d0;
      i0 = c0 ? pi : i0;
    }
  }
  float inv = 1.0f / rsum;
  size_t base = (size_t)gid * 3;
  w3[base + 0] = rsqrtf(d0 + 1e-16f) * inv;
  w3[base + 1] = rsqrtf(d1 + 1e-16f) * inv;
  w3[base + 2] = rsqrtf(d2 + 1e-16f) * inv;
  idx3[base + 0] = i0; idx3[base + 1] = i1; idx3[base + 2] = i2;
}

// GEMM1: y1[o][n] = sum_c W1[o][c] * x[c][n], x = [interp(256); skip(128)].
// Writes y1 transposed: y1T[b][n][o]. Accumulates BN stats per channel o.
__global__ __launch_bounds__(256) void gemm1_kernel(
    const float* __restrict__ points_prev, const float* __restrict__ points_skip,
    const float* __restrict__ W1, const float* __restrict__ w3,
    const int* __restrict__ idx3, float* __restrict__ y1T,
    float* __restrict__ stats1) {
  __shared__ float Ws[16][CO];
  __shared__ float xs[16][68];
  __shared__ float w3s[64][3];
  __shared__ int   idx3s[64][3];
  __shared__ float ssum[CO], ssq[CO];
  int tid = threadIdx.x;
  int n0 = blockIdx.x * 64;
  int b = blockIdx.y;
  if (tid < 192) {
    size_t base = ((size_t)b * NS + n0) * 3;
    w3s[tid / 3][tid % 3] = w3[base + tid];
    idx3s[tid / 3][tid % 3] = idx3[base + tid];
  }
  ssum[tid] = 0.f; ssq[tid] = 0.f;
  __syncthreads();
  const float* PP = points_prev + (size_t)b * CP * NP;
  const float* PS = points_skip + (size_t)b * CS * NS;
  float acc[8][8];
  #pragma unroll
  for (int m = 0; m < 8; m++)
    #pragma unroll
    for (int i = 0; i < 8; i++) acc[m][i] = 0.f;
  int tx = tid & 31, ty = tid >> 5;
  for (int kc = 0; kc < CIN; kc += 16) {
    { // load W tile [16 c][256 o]
      int qd = tid & 3, orow = tid >> 2;
      #pragma unroll
      for (int r = 0; r < 4; r++) {
        int o = r * 64 + orow;
        const float4 v = *(const float4*)(W1 + (size_t)o * CIN + kc + qd * 4);
        Ws[qd * 4 + 0][o] = v.x; Ws[qd * 4 + 1][o] = v.y;
        Ws[qd * 4 + 2][o] = v.z; Ws[qd * 4 + 3][o] = v.w;
      }
    }
    { // load x tile [16 c][64 n] on the fly
      int k = tid & 15, nl = (tid >> 4) * 4, c = kc + k;
      if (c < CP) {
        const float* row = PP + (size_t)c * NP;
        #pragma unroll
        for (int q2 = 0; q2 < 4; q2++) {
          int nn = nl + q2;
          float v = w3s[nn][0] * row[idx3s[nn][0]]
                  + w3s[nn][1] * row[idx3s[nn][1]]
                  + w3s[nn][2] * row[idx3s[nn][2]];
          xs[k][nn] = v;
        }
      } else {
        const float4 v = *(const float4*)(PS + (size_t)(c - CP) * NS + n0 + nl);
        xs[k][nl] = v.x; xs[k][nl + 1] = v.y; xs[k][nl + 2] = v.z; xs[k][nl + 3] = v.w;
      }
    }
    __syncthreads();
    #pragma unroll
    for (int k = 0; k < 16; k++) {
      float wr[8], xr[8];
      #pragma unroll
      for (int m = 0; m < 8; m++) wr[m] = Ws[k][tx + 32 * m];
      #pragma unroll
      for (int i = 0; i < 8; i++) xr[i] = xs[k][ty * 8 + i];
      #pragma unroll
      for (int m = 0; m < 8; m++)
        #pragma unroll
        for (int i = 0; i < 8; i++) acc[m][i] = fmaf(wr[m], xr[i], acc[m][i]);
    }
    __syncthreads();
  }
  #pragma unroll
  for (int m = 0; m < 8; m++) {
    float ps = 0.f, pq = 0.f;
    #pragma unroll
    for (int i = 0; i < 8; i++) { float v = acc[m][i]; ps += v; pq += v * v; }
    atomicAdd(&ssum[tx + 32 * m], ps);
    atomicAdd(&ssq[tx + 32 * m], pq);
  }
  float* Y = y1T + (size_t)b * NS * CO;
  #pragma unroll
  for (int i = 0; i < 8; i++) {
    int n = n0 + ty * 8 + i;
    float* yr = Y + (size_t)n * CO + tx;
    #pragma unroll
    for (int m = 0; m < 8; m++) yr[32 * m] = acc[m][i];
  }
  __syncthreads();
  atomicAdd(&stats1[tid], ssum[tid]);
  atomicAdd(&stats1[CO + tid], ssq[tid]);
}

// stats -> per-channel affine: z = a*y + s, then relu
__global__ void bnstats_kernel(const float* __restrict__ stats,
                               const float* __restrict__ g,
                               const float* __restrict__ bt,
                               float* __restrict__ a, float* __restrict__ s) {
  int o = threadIdx.x;
  float cnt = (float)NB * (float)NS;
  float m = stats[o] / cnt;
  float var = stats[CO + o] / cnt - m * m;
  var = fmaxf(var, 0.f);
  float inv = rsqrtf(var + 1e-5f);
  float av = g[o] * inv;
  a[o] = av; s[o] = bt[o] - m * av;
}

// GEMM2: y2[o][n] = sum_c W2[o][c] * relu(a1[c]*y1[c][n]+s1[c]); y2 transposed out.
__global__ __launch_bounds__(256) void gemm2_kernel(
    const float* __restrict__ y1T, const float* __restrict__ W2,
    const float* __restrict__ a1, const float* __restrict__ s1,
    float* __restrict__ y2T, float* __restrict__ stats2) {
  __shared__ float Ws[16][CO];
  __shared__ float xs[16][68];
  __shared__ float ssum[CO], ssq[CO];
  int tid = threadIdx.x;
  int n0 = blockIdx.x * 64;
  int b = blockIdx.y;
  ssum[tid] = 0.f; ssq[tid] = 0.f;
  __syncthreads();
  const float* Y1 = y1T + (size_t)b * NS * CO;
  float acc[8][8];
  #pragma unroll
  for (int m = 0; m < 8; m++)
    #pragma unroll
    for (int i = 0; i < 8; i++) acc[m][i] = 0.f;
  int tx = tid & 31, ty = tid >> 5;
  for (int kc = 0; kc < CO; kc += 16) {
    {
      int qd = tid & 3, orow = tid >> 2;
      #pragma unroll
      for (int r = 0; r < 4; r++) {
        int o = r * 64 + orow;
        const float4 v = *(const float4*)(W2 + (size_t)o * CO + kc + qd * 4);
        Ws[qd * 4 + 0][o] = v.x; Ws[qd * 4 + 1][o] = v.y;
        Ws[qd * 4 + 2][o] = v.z; Ws[qd * 4 + 3][o] = v.w;
      }
    }
    {
      int k = tid & 15, nl = (tid >> 4) * 4, c = kc + k;
      float ac = a1[c], sc = s1[c];
      #pragma unroll
      for (int q2 = 0; q2 < 4; q2++) {
        float v = Y1[(size_t)(n0 + nl + q2) * CO + c];
        xs[k][nl + q2] = fmaxf(fmaf(ac, v, sc), 0.f);
      }
    }
    __syncthreads();
    #pragma unroll
    for (int k = 0; k < 16; k++) {
      float wr[8], xr[8];
      #pragma unroll
      for (int m = 0; m < 8; m++) wr[m] = Ws[k][tx + 32 * m];
      #pragma unroll
      for (int i = 0; i < 8; i++) xr[i] = xs[k][ty * 8 + i];
      #pragma unroll
      for (int m = 0; m < 8; m++)
        #pragma unroll
        for (int i = 0; i < 8; i++) acc[m][i] = fmaf(wr[m], xr[i], acc[m][i]);
    }
    __syncthreads();
  }
  #pragma unroll
  for (int m = 0; m < 8; m++) {
    float ps = 0.f, pq = 0.f;
    #pragma unroll
    for (int i = 0; i < 8; i++) { float v = acc[m][i]; ps += v; pq += v * v; }
    atomicAdd(&ssum[tx + 32 * m], ps);
    atomicAdd(&ssq[tx + 32 * m], pq);
  }
  float* Y = y2T + (size_t)b * NS * CO;
  #pragma unroll
  for (int i = 0; i < 8; i++) {
    int n = n0 + ty * 8 + i;
    float* yr = Y + (size_t)n * CO + tx;
    #pragma unroll
    for (int m = 0; m < 8; m++) yr[32 * m] = acc[m][i];
  }
  __syncthreads();
  atomicAdd(&stats2[tid], ssum[tid]);
  atomicAdd(&stats2[CO + tid], ssq[tid]);
}

// Final BN2+ReLU with transpose [b][n][o] -> [b][o][n] via LDS tile.
__global__ __launch_bounds__(256) void bnrelu_tr_kernel(
    const float* __restrict__ y2T, const float* __restrict__ a2,
    const float* __restrict__ s2, float* __restrict__ out) {
  __shared__ float tl[64][65];
  int n0 = blockIdx.x * 64, o0 = blockIdx.y * 64, b = blockIdx.z;
  const float* Y = y2T + (size_t)b * NS * CO;
  int tid = threadIdx.x;
  int j4 = (tid & 15) * 4, i = tid >> 4;
  #pragma unroll
  for (int r = 0; r < 4; r++) {
    int ii = i + 16 * r;
    float4 v = *(const float4*)(Y + (size_t)(n0 + ii) * CO + o0 + j4);
    tl[ii][j4] = v.x; tl[ii][j4 + 1] = v.y; tl[ii][j4 + 2] = v.z; tl[ii][j4 + 3] = v.w;
  }
  __syncthreads();
  float* O = out + (size_t)b * CO * NS;
  int ii4 = (tid & 15) * 4, j = tid >> 4;
  #pragma unroll
  for (int r = 0; r < 4; r++) {
    int jj = j + 16 * r;
    float av = a2[o0 + jj], sv = s2[o0 + jj];
    float4 v;
    v.x = fmaxf(fmaf(av, tl[ii4 + 0][jj], sv), 0.f);
    v.y = fmaxf(fmaf(av, tl[ii4 + 1][jj], sv), 0.f);
    v.z = fmaxf(fmaf(av, tl[ii4 + 2][jj], sv), 0.f);
    v.w = fmaxf(fmaf(av, tl[ii4 + 3][jj], sv), 0.f);
    *(float4*)(O + (size_t)(o0 + jj) * NS + n0 + ii4) = v;
  }
}

__global__ void zero_kernel(float* st1, float* st2) {
  int t = threadIdx.x;
  if (t < 512) { st1[t] = 0.f; st2[t] = 0.f; }
}

extern "C" void kernel_launch(void* const* d_in, const int* in_sizes, int n_in,
                              void* d_out, int out_size, void* d_ws, size_t ws_size,
                              hipStream_t stream) {
  const float* xyz_prev    = (const float*)d_in[0];
  const float* xyz_skip    = (const float*)d_in[1];
  const float* points_prev = (const float*)d_in[2];
  const float* points_skip = (const float*)d_in[3];
  const float* W1 = (const float*)d_in[4];
  const float* g1 = (const float*)d_in[5];
  const float* b1 = (const float*)d_in[6];
  const float* W2 = (const float*)d_in[7];
  const float* g2 = (const float*)d_in[8];
  const float* b2 = (const float*)d_in[9];
  float* out = (float*)d_out;

  const size_t ybuf = (size_t)NB * NS * CO;           // 16.78M floats
  const size_t full_need = (2 * ybuf + 2 * (size_t)NB * NS * 3 + 4096) * 4;

  float* y1T = (float*)d_ws;
  float* y2T;
  float* tail;
  bool compact = (ws_size < full_need);
  if (!compact) {
    y2T = y1T + ybuf;
    tail = y2T + ybuf;
  } else {
    y2T = out;          // y2 (transposed layout) lives in d_out
    tail = y1T + ybuf;
  }
  // pbuf aliases the y1T region: consumed by topk_merge BEFORE gemm1 writes y1T
  float* pbuf = (float*)d_ws;   // NB*NCHUNK*NS*8 floats = 4.19M <= ybuf
  float* w3 = tail;
  int* idx3 = (int*)(w3 + (size_t)NB * NS * 3);
  float* st1 = (float*)(idx3 + (size_t)NB * NS * 3);
  float* st2 = st1 + 512;
  float* a1 = st2 + 512; float* s1 = a1 + CO;
  float* a2 = s1 + CO;   float* s2 = a2 + CO;

  hipLaunchKernelGGL(zero_kernel, dim3(1), dim3(512), 0, stream, st1, st2);
  hipLaunchKernelGGL(topk_chunk_kernel, dim3(NS / 256, NCHUNK, NB), dim3(256), 0,
                     stream, xyz_prev, xyz_skip, pbuf);
  hipLaunchKernelGGL(topk_merge_kernel, dim3(NB * NS / 256), dim3(256), 0, stream,
                     pbuf, w3, idx3);
  hipLaunchKernelGGL(gemm1_kernel, dim3(NS / 64, NB), dim3(256), 0, stream,
                     points_prev, points_skip, W1, w3, idx3, y1T, st1);
  hipLaunchKernelGGL(bnstats_kernel, dim3(1), dim3(256), 0, stream, st1, g1, b1, a1, s1);
  hipLaunchKernelGGL(gemm2_kernel, dim3(NS / 64, NB), dim3(256), 0, stream,
                     y1T, W2, a1, s1, y2T, st2);
  hipLaunchKernelGGL(bnstats_kernel, dim3(1), dim3(256), 0, stream, st2, g2, b2, a2, s2);
  if (!compact) {
    hipLaunchKernelGGL(bnrelu_tr_kernel, dim3(NS / 64, CO / 64, NB), dim3(256), 0, stream,
                       y2T, a2, s2, out);
  } else {
    hipLaunchKernelGGL(bnrelu_tr_kernel, dim3(NS / 64, CO / 64, NB), dim3(256), 0, stream,
                       y2T, a2, s2, y1T);
    hipMemcpyAsync(out, y1T, ybuf * 4, hipMemcpyDeviceToDevice, stream);
  }
}

// Round 3
// 199.939 us; speedup vs baseline: 4.4816x; 2.2984x over previous
//
#include <hip/hip_runtime.h>
#include <math.h>

// Problem dims (fixed by the reference)
constexpr int NB  = 16;    // batch
constexpr int NP  = 1024;  // prev points
constexpr int NS  = 4096;  // skip points
constexpr int CP  = 256;   // prev channels
constexpr int CS  = 128;   // skip channels
constexpr int CIN = 384;   // CP + CS
constexpr int CO  = 256;   // output channels

constexpr int NCHUNK = 8;           // prev-point chunks for topk parallelism
constexpr int CHPTS  = NP / NCHUNK; // 128

typedef unsigned int uint;
typedef unsigned short ushort_t;
typedef __attribute__((ext_vector_type(8))) short short8;
typedef __attribute__((ext_vector_type(4))) float f32x4;

__device__ __forceinline__ ushort_t f2bf(float f) {
  uint u = __float_as_uint(f);
  uint r = (u + 0x7fffu + ((u >> 16) & 1u)) >> 16;   // RNE
  return (ushort_t)r;
}
__device__ __forceinline__ float bf2f(ushort_t u) {
  return __uint_as_float(((uint)u) << 16);
}

__device__ __forceinline__ void gload16(const void* g, void* l) {
  __builtin_amdgcn_global_load_lds(
      (const __attribute__((address_space(1))) uint*)g,
      (__attribute__((address_space(3))) uint*)l, 16, 0, 0);
}

// ---------------------------------------------------------------------------
// topk stage 1 (unchanged from round 2)
__global__ __launch_bounds__(256) void topk_chunk_kernel(
    const float* __restrict__ xyz_prev, const float* __restrict__ xyz_skip,
    float* __restrict__ pbuf) {
  __shared__ float px[CHPTS], py[CHPTS], pz[CHPTS];
  int ng = blockIdx.x;
  int q  = blockIdx.y;
  int b  = blockIdx.z;
  int tid = threadIdx.x;
  if (tid < CHPTS) {
    const float* xp = xyz_prev + ((size_t)b * NP + q * CHPTS + tid) * 3;
    px[tid] = xp[0]; py[tid] = xp[1]; pz[tid] = xp[2];
  }
  __syncthreads();
  int n = ng * 256 + tid;
  const float* xq = xyz_skip + ((size_t)b * NS + n) * 3;
  float qx = xq[0], qy = xq[1], qz = xq[2];
  float d0 = INFINITY, d1 = INFINITY, d2 = INFINITY;
  int i0 = -1, i1 = -1, i2 = -1;
  float rsum = 0.f;
  int pbase = q * CHPTS;
  #pragma unroll 8
  for (int p = 0; p < CHPTS; p++) {
    float dx = px[p] - qx, dy = py[p] - qy, dz = pz[p] - qz;
    float sq = fmaf(dz, dz, fmaf(dy, dy, dx * dx));
    rsum += rsqrtf(sq + 1e-16f);
    bool c0 = sq < d0, c1 = sq < d1, c2 = sq < d2;
    int pi = pbase + p;
    d2 = c2 ? (c1 ? d1 : sq) : d2;
    i2 = c2 ? (c1 ? i1 : pi) : i2;
    d1 = c1 ? (c0 ? d0 : sq) : d1;
    i1 = c1 ? (c0 ? i0 : pi) : i1;
    d0 = c0 ? sq : d0;
    i0 = c0 ? pi : i0;
  }
  size_t P = ((size_t)(b * NCHUNK + q) * NS + n) * 8;
  float4 v0 = make_float4(d0, d1, d2, rsum);
  float4 v1;
  v1.x = __int_as_float(i0); v1.y = __int_as_float(i1);
  v1.z = __int_as_float(i2); v1.w = 0.f;
  *(float4*)(pbuf + P) = v0;
  *(float4*)(pbuf + P + 4) = v1;
}

// topk stage 2 (unchanged)
__global__ __launch_bounds__(256) void topk_merge_kernel(
    const float* __restrict__ pbuf, float* __restrict__ w3,
    int* __restrict__ idx3) {
  int gid = blockIdx.x * 256 + threadIdx.x;  // = b*NS + n
  int b = gid >> 12;
  int n = gid & (NS - 1);
  float d0 = INFINITY, d1 = INFINITY, d2 = INFINITY;
  int i0 = -1, i1 = -1, i2 = -1;
  float rsum = 0.f;
  for (int q = 0; q < NCHUNK; q++) {
    size_t P = ((size_t)(b * NCHUNK + q) * NS + n) * 8;
    float4 v0 = *(const float4*)(pbuf + P);
    float4 v1 = *(const float4*)(pbuf + P + 4);
    rsum += v0.w;
    float ds[3] = {v0.x, v0.y, v0.z};
    int   is[3] = {__float_as_int(v1.x), __float_as_int(v1.y),
                   __float_as_int(v1.z)};
    #pragma unroll
    for (int k = 0; k < 3; k++) {
      float sq = ds[k]; int pi = is[k];
      bool c0 = sq < d0, c1 = sq < d1, c2 = sq < d2;
      d2 = c2 ? (c1 ? d1 : sq) : d2;
      i2 = c2 ? (c1 ? i1 : pi) : i2;
      d1 = c1 ? (c0 ? d0 : sq) : d1;
      i1 = c1 ? (c0 ? i0 : pi) : i1;
      d0 = c0 ? sq : d0;
      i0 = c0 ? pi : i0;
    }
  }
  float inv = 1.0f / rsum;
  size_t base = (size_t)gid * 3;
  w3[base + 0] = rsqrtf(d0 + 1e-16f) * inv;
  w3[base + 1] = rsqrtf(d1 + 1e-16f) * inv;
  w3[base + 2] = rsqrtf(d2 + 1e-16f) * inv;
  idx3[base + 0] = i0; idx3[base + 1] = i1; idx3[base + 2] = i2;
}

// ---------------------------------------------------------------------------
// W fp32 -> bf16 (both weight matrices), vectorized float4 -> ushort4.
__global__ __launch_bounds__(256) void wcast_kernel(
    const float* __restrict__ W1, const float* __restrict__ W2,
    ushort_t* __restrict__ W1b, ushort_t* __restrict__ W2b) {
  int t = blockIdx.x * 256 + threadIdx.x;   // 40960 threads, 4 elems each
  int n1 = CO * CIN / 4;                    // 24576
  if (t < n1) {
    float4 v = *(const float4*)(W1 + t * 4);
    ushort4 o; o.x = f2bf(v.x); o.y = f2bf(v.y); o.z = f2bf(v.z); o.w = f2bf(v.w);
    *(ushort4*)(W1b + t * 4) = o;
  } else {
    int u = t - n1;                         // < 16384
    float4 v = *(const float4*)(W2 + u * 4);
    ushort4 o; o.x = f2bf(v.x); o.y = f2bf(v.y); o.z = f2bf(v.z); o.w = f2bf(v.w);
    *(ushort4*)(W2b + u * 4) = o;
  }
}

// ---------------------------------------------------------------------------
// Transpose points_prev [b][256][1024] f32 -> pptT [b][1024][256] bf16.
// grid (NP/64, CP/64, NB), block 256, 64x64 tiles.
__global__ __launch_bounds__(256) void ppT_kernel(
    const float* __restrict__ pp, ushort_t* __restrict__ pptT) {
  __shared__ float tl[64][65];
  int p0 = blockIdx.x * 64, c0 = blockIdx.y * 64, b = blockIdx.z;
  int tid = threadIdx.x;
  const float* P = pp + (size_t)b * CP * NP;
  int pi4 = (tid & 15) * 4, ci = tid >> 4;
  #pragma unroll
  for (int r = 0; r < 4; r++) {
    int cc = ci + 16 * r;
    float4 v = *(const float4*)(P + (size_t)(c0 + cc) * NP + p0 + pi4);
    tl[cc][pi4] = v.x; tl[cc][pi4 + 1] = v.y; tl[cc][pi4 + 2] = v.z; tl[cc][pi4 + 3] = v.w;
  }
  __syncthreads();
  ushort_t* O = pptT + (size_t)b * NP * CP;
  int ci4 = (tid & 15) * 4, pi = tid >> 4;
  #pragma unroll
  for (int r = 0; r < 4; r++) {
    int pr = pi + 16 * r;
    ushort4 o;
    o.x = f2bf(tl[ci4 + 0][pr]); o.y = f2bf(tl[ci4 + 1][pr]);
    o.z = f2bf(tl[ci4 + 2][pr]); o.w = f2bf(tl[ci4 + 3][pr]);
    *(ushort4*)(O + (size_t)(p0 + pr) * CP + c0 + ci4) = o;
  }
}

// Transpose points_skip [b][128][4096] f32 -> x1[b][n][256..383] bf16.
// grid (NS/64, CS/64, NB), block 256.
__global__ __launch_bounds__(256) void skipT_kernel(
    const float* __restrict__ sk, ushort_t* __restrict__ x1) {
  __shared__ float tl[64][65];
  int n0 = blockIdx.x * 64, c0 = blockIdx.y * 64, b = blockIdx.z;
  int tid = threadIdx.x;
  const float* S = sk + (size_t)b * CS * NS;
  int ni4 = (tid & 15) * 4, ci = tid >> 4;
  #pragma unroll
  for (int r = 0; r < 4; r++) {
    int cc = ci + 16 * r;
    float4 v = *(const float4*)(S + (size_t)(c0 + cc) * NS + n0 + ni4);
    tl[cc][ni4] = v.x; tl[cc][ni4 + 1] = v.y; tl[cc][ni4 + 2] = v.z; tl[cc][ni4 + 3] = v.w;
  }
  __syncthreads();
  ushort_t* O = x1 + (size_t)b * NS * CIN;
  int ci4 = (tid & 15) * 4, ni = tid >> 4;
  #pragma unroll
  for (int r = 0; r < 4; r++) {
    int nr = ni + 16 * r;
    ushort4 o;
    o.x = f2bf(tl[ci4 + 0][nr]); o.y = f2bf(tl[ci4 + 1][nr]);
    o.z = f2bf(tl[ci4 + 2][nr]); o.w = f2bf(tl[ci4 + 3][nr]);
    *(ushort4*)(O + (size_t)(n0 + nr) * CIN + CP + c0 + ci4) = o;
  }
}

// Interp: x1[b][n][0..255] = sum_k w3[k] * pptT[idx[k]][c].  64 lanes per n,
// 4 c per lane. grid (NS/4, NB), block 256.
__global__ __launch_bounds__(256) void interp_kernel(
    const ushort_t* __restrict__ pptT, const float* __restrict__ w3,
    const int* __restrict__ idx3, ushort_t* __restrict__ x1) {
  int tid = threadIdx.x;
  int nl = tid >> 6, l = tid & 63;
  int b = blockIdx.y;
  int n = blockIdx.x * 4 + nl;
  size_t nb = (size_t)b * NS + n;
  int j0 = idx3[nb * 3 + 0], j1 = idx3[nb * 3 + 1], j2 = idx3[nb * 3 + 2];
  float w0 = w3[nb * 3 + 0], w1 = w3[nb * 3 + 1], w2 = w3[nb * 3 + 2];
  const ushort_t* P = pptT + (size_t)b * NP * CP;
  int c = l * 4;
  ushort4 g0 = *(const ushort4*)(P + (size_t)j0 * CP + c);
  ushort4 g1 = *(const ushort4*)(P + (size_t)j1 * CP + c);
  ushort4 g2 = *(const ushort4*)(P + (size_t)j2 * CP + c);
  ushort4 o;
  o.x = f2bf(w0 * bf2f(g0.x) + w1 * bf2f(g1.x) + w2 * bf2f(g2.x));
  o.y = f2bf(w0 * bf2f(g0.y) + w1 * bf2f(g1.y) + w2 * bf2f(g2.y));
  o.z = f2bf(w0 * bf2f(g0.z) + w1 * bf2f(g1.z) + w2 * bf2f(g2.z));
  o.w = f2bf(w0 * bf2f(g0.w) + w1 * bf2f(g1.w) + w2 * bf2f(g2.w));
  *(ushort4*)(x1 + nb * CIN + c) = o;
}

// ---------------------------------------------------------------------------
// MFMA GEMM: D[b][n][o] = X[b][n][:] . Wb[o][:]  (K = KD), bf16 inputs,
// fp32 accumulate. 128x128 tile, 4 waves, 4x4 frags of 16x16x32.
// Writes bf16 (OUT_BF16) or fp32, accumulates BN stats (sum, sumsq per o).
template <int KD, bool OUT_BF16>
__global__ __launch_bounds__(256) void gemm_mfma_kernel(
    const ushort_t* __restrict__ X, const ushort_t* __restrict__ Wb,
    ushort_t* __restrict__ Yb, float* __restrict__ Yf,
    float* __restrict__ stats) {
  __shared__ ushort_t ldsX[128 * 32];
  __shared__ ushort_t ldsW[128 * 32];
  __shared__ float ssum[128], ssq[128];
  int tid = threadIdx.x;
  int w = tid >> 6, l = tid & 63;
  int n0 = blockIdx.x * 128;
  int by = blockIdx.y;           // m-tile (o block of 128)
  int bz = blockIdx.z;           // batch
  if (tid < 128) { ssum[tid] = 0.f; ssq[tid] = 0.f; }

  f32x4 acc[4][4];
  #pragma unroll
  for (int i = 0; i < 4; i++)
    #pragma unroll
    for (int j = 0; j < 4; j++) acc[i][j] = {0.f, 0.f, 0.f, 0.f};

  int wn = (w & 1) * 64, wo = (w >> 1) * 64;
  int lr = l & 15, lk = l >> 4;
  const ushort_t* Xb = X + (size_t)bz * NS * KD;

  for (int kt = 0; kt < KD / 32; kt++) {
    int k0 = kt * 32;
    // stage X tile [128 n][32 k] and W tile [128 o][32 k], source pre-swizzled
    #pragma unroll
    for (int q = 0; q < 2; q++) {
      int r = q * 64 + w * 16 + (l >> 2);
      int cl = l & 3;
      int ks = k0 + 8 * (cl ^ ((r >> 1) & 3));
      gload16(Xb + (size_t)(n0 + r) * KD + ks, &ldsX[(q * 64 + w * 16) * 32]);
      gload16(Wb + (size_t)(by * 128 + r) * KD + ks, &ldsW[(q * 64 + w * 16) * 32]);
    }
    __syncthreads();
    short8 a[4], bfr[4];
    #pragma unroll
    for (int i = 0; i < 4; i++) {
      int rr = wn + i * 16 + lr;
      int cs = lk ^ ((rr >> 1) & 3);
      a[i] = *(const short8*)&ldsX[rr * 32 + cs * 8];
    }
    #pragma unroll
    for (int j = 0; j < 4; j++) {
      int rr = wo + j * 16 + lr;
      int cs = lk ^ ((rr >> 1) & 3);
      bfr[j] = *(const short8*)&ldsW[rr * 32 + cs * 8];
    }
    #pragma unroll
    for (int i = 0; i < 4; i++)
      #pragma unroll
      for (int j = 0; j < 4; j++)
        acc[i][j] = __builtin_amdgcn_mfma_f32_16x16x32_bf16(a[i], bfr[j], acc[i][j], 0, 0, 0);
    __syncthreads();
  }

  // epilogue: D frag mapping col=lane&15 (o), row=(lane>>4)*4+reg (n)
  #pragma unroll
  for (int j = 0; j < 4; j++) {
    int ol = wo + j * 16 + lr;
    int og = by * 128 + ol;
    float ps = 0.f, pq = 0.f;
    #pragma unroll
    for (int i = 0; i < 4; i++) {
      #pragma unroll
      for (int rg = 0; rg < 4; rg++) {
        float v = acc[i][j][rg];
        ps += v; pq += v * v;
        int n = n0 + wn + i * 16 + lk * 4 + rg;
        size_t off = ((size_t)bz * NS + n) * CO + og;
        if (OUT_BF16) Yb[off] = f2bf(v);
        else Yf[off] = v;
      }
    }
    atomicAdd(&ssum[ol], ps);
    atomicAdd(&ssq[ol], pq);
  }
  __syncthreads();
  if (tid < 128) {
    atomicAdd(&stats[by * 128 + tid], ssum[tid]);
    atomicAdd(&stats[CO + by * 128 + tid], ssq[tid]);
  }
}

// stats -> per-channel affine
__global__ void bnstats_kernel(const float* __restrict__ stats,
                               const float* __restrict__ g,
                               const float* __restrict__ bt,
                               float* __restrict__ a, float* __restrict__ s) {
  int o = threadIdx.x;
  float cnt = (float)NB * (float)NS;
  float m = stats[o] / cnt;
  float var = stats[CO + o] / cnt - m * m;
  var = fmaxf(var, 0.f);
  float inv = rsqrtf(var + 1e-5f);
  float av = g[o] * inv;
  a[o] = av; s[o] = bt[o] - m * av;
}

// In-place BN+ReLU on y1bf [b][n][256] bf16: y = relu(a[o]*y + s[o])
__global__ __launch_bounds__(256) void act_kernel(
    ushort_t* __restrict__ y, const float* __restrict__ a,
    const float* __restrict__ s) {
  size_t i = ((size_t)blockIdx.x * 256 + threadIdx.x) * 8;
  int o = (int)(i & (CO - 1));
  ushort4 v0 = *(ushort4*)(y + i), v1 = *(ushort4*)(y + i + 4);
  ushort4 r0, r1;
  r0.x = f2bf(fmaxf(fmaf(a[o + 0], bf2f(v0.x), s[o + 0]), 0.f));
  r0.y = f2bf(fmaxf(fmaf(a[o + 1], bf2f(v0.y), s[o + 1]), 0.f));
  r0.z = f2bf(fmaxf(fmaf(a[o + 2], bf2f(v0.z), s[o + 2]), 0.f));
  r0.w = f2bf(fmaxf(fmaf(a[o + 3], bf2f(v0.w), s[o + 3]), 0.f));
  r1.x = f2bf(fmaxf(fmaf(a[o + 4], bf2f(v1.x), s[o + 4]), 0.f));
  r1.y = f2bf(fmaxf(fmaf(a[o + 5], bf2f(v1.y), s[o + 5]), 0.f));
  r1.z = f2bf(fmaxf(fmaf(a[o + 6], bf2f(v1.z), s[o + 6]), 0.f));
  r1.w = f2bf(fmaxf(fmaf(a[o + 7], bf2f(v1.w), s[o + 7]), 0.f));
  *(ushort4*)(y + i) = r0;
  *(ushort4*)(y + i + 4) = r1;
}

// Final BN2+ReLU with transpose [b][n][o] -> [b][o][n] via LDS tile (fp32 in).
__global__ __launch_bounds__(256) void bnrelu_tr_kernel(
    const float* __restrict__ y2T, const float* __restrict__ a2,
    const float* __restrict__ s2, float* __restrict__ out) {
  __shared__ float tl[64][65];
  int n0 = blockIdx.x * 64, o0 = blockIdx.y * 64, b = blockIdx.z;
  const float* Y = y2T + (size_t)b * NS * CO;
  int tid = threadIdx.x;
  int j4 = (tid & 15) * 4, i = tid >> 4;
  #pragma unroll
  for (int r = 0; r < 4; r++) {
    int ii = i + 16 * r;
    float4 v = *(const float4*)(Y + (size_t)(n0 + ii) * CO + o0 + j4);
    tl[ii][j4] = v.x; tl[ii][j4 + 1] = v.y; tl[ii][j4 + 2] = v.z; tl[ii][j4 + 3] = v.w;
  }
  __syncthreads();
  float* O = out + (size_t)b * CO * NS;
  int ii4 = (tid & 15) * 4, j = tid >> 4;
  #pragma unroll
  for (int r = 0; r < 4; r++) {
    int jj = j + 16 * r;
    float av = a2[o0 + jj], sv = s2[o0 + jj];
    float4 v;
    v.x = fmaxf(fmaf(av, tl[ii4 + 0][jj], sv), 0.f);
    v.y = fmaxf(fmaf(av, tl[ii4 + 1][jj], sv), 0.f);
    v.z = fmaxf(fmaf(av, tl[ii4 + 2][jj], sv), 0.f);
    v.w = fmaxf(fmaf(av, tl[ii4 + 3][jj], sv), 0.f);
    *(float4*)(O + (size_t)(o0 + jj) * NS + n0 + ii4) = v;
  }
}

__global__ void zero_kernel(float* st1, float* st2) {
  int t = threadIdx.x;
  if (t < 512) { st1[t] = 0.f; st2[t] = 0.f; }
}

extern "C" void kernel_launch(void* const* d_in, const int* in_sizes, int n_in,
                              void* d_out, int out_size, void* d_ws, size_t ws_size,
                              hipStream_t stream) {
  const float* xyz_prev    = (const float*)d_in[0];
  const float* xyz_skip    = (const float*)d_in[1];
  const float* points_prev = (const float*)d_in[2];
  const float* points_skip = (const float*)d_in[3];
  const float* W1 = (const float*)d_in[4];
  const float* g1 = (const float*)d_in[5];
  const float* b1 = (const float*)d_in[6];
  const float* W2 = (const float*)d_in[7];
  const float* g2 = (const float*)d_in[8];
  const float* b2 = (const float*)d_in[9];
  float* out = (float*)d_out;

  // workspace layout (256B-aligned sequential allocs)
  char* W = (char*)d_ws;
  size_t off = 0;
  auto alloc = [&](size_t bytes) {
    size_t o = off; off = (off + bytes + 255) & ~(size_t)255; return o;
  };
  ushort_t* x1   = (ushort_t*)(W + alloc((size_t)NB * NS * CIN * 2));  // 50.3MB
  ushort_t* y1b  = (ushort_t*)(W + alloc((size_t)NB * NS * CO * 2));   // 33.6MB
  ushort_t* pptT = (ushort_t*)(W + alloc((size_t)NB * NP * CP * 2));   // 8.4MB
  ushort_t* W1b  = (ushort_t*)(W + alloc((size_t)CO * CIN * 2));
  ushort_t* W2b  = (ushort_t*)(W + alloc((size_t)CO * CO * 2));
  float* w3   = (float*)(W + alloc((size_t)NB * NS * 3 * 4));
  int*   idx3 = (int*)(W + alloc((size_t)NB * NS * 3 * 4));
  float* st1  = (float*)(W + alloc(512 * 4));
  float* st2  = (float*)(W + alloc(512 * 4));
  float* ab   = (float*)(W + alloc(1024 * 4));
  float* a1 = ab, *s1 = ab + 256, *a2 = ab + 512, *s2 = ab + 768;
  size_t y2_off = alloc((size_t)NB * NS * CO * 4);                     // 67.1MB
  bool full = (ws_size >= off);
  float* y2f  = full ? (float*)(W + y2_off) : (float*)d_out;
  // pbuf (16.8MB, transient) aliases the y2 region (written much later)
  float* pbuf = y2f;

  hipLaunchKernelGGL(zero_kernel, dim3(1), dim3(512), 0, stream, st1, st2);
  hipLaunchKernelGGL(topk_chunk_kernel, dim3(NS / 256, NCHUNK, NB), dim3(256), 0,
                     stream, xyz_prev, xyz_skip, pbuf);
  hipLaunchKernelGGL(topk_merge_kernel, dim3(NB * NS / 256), dim3(256), 0, stream,
                     pbuf, w3, idx3);
  hipLaunchKernelGGL(wcast_kernel, dim3((CO * CIN / 4 + CO * CO / 4 + 255) / 256),
                     dim3(256), 0, stream, W1, W2, W1b, W2b);
  hipLaunchKernelGGL(ppT_kernel, dim3(NP / 64, CP / 64, NB), dim3(256), 0, stream,
                     points_prev, pptT);
  hipLaunchKernelGGL(skipT_kernel, dim3(NS / 64, CS / 64, NB), dim3(256), 0, stream,
                     points_skip, x1);
  hipLaunchKernelGGL(interp_kernel, dim3(NS / 4, NB), dim3(256), 0, stream,
                     pptT, w3, idx3, x1);
  hipLaunchKernelGGL((gemm_mfma_kernel<CIN, true>), dim3(NS / 128, 2, NB), dim3(256),
                     0, stream, x1, W1b, y1b, (float*)nullptr, st1);
  hipLaunchKernelGGL(bnstats_kernel, dim3(1), dim3(256), 0, stream, st1, g1, b1, a1, s1);
  hipLaunchKernelGGL(act_kernel, dim3((int)((size_t)NB * NS * CO / 8 / 256)),
                     dim3(256), 0, stream, y1b, a1, s1);
  hipLaunchKernelGGL((gemm_mfma_kernel<CO, false>), dim3(NS / 128, 2, NB), dim3(256),
                     0, stream, y1b, W2b, (ushort_t*)nullptr, y2f, st2);
  hipLaunchKernelGGL(bnstats_kernel, dim3(1), dim3(256), 0, stream, st2, g2, b2, a2, s2);
  if (full) {
    hipLaunchKernelGGL(bnrelu_tr_kernel, dim3(NS / 64, CO / 64, NB), dim3(256), 0,
                       stream, y2f, a2, s2, out);
  } else {
    // y2f == d_out: stage final into ws (x1+y1b region, dead) then copy back
    float* stage = (float*)d_ws;
    hipLaunchKernelGGL(bnrelu_tr_kernel, dim3(NS / 64, CO / 64, NB), dim3(256), 0,
                       stream, y2f, a2, s2, stage);
    hipMemcpyAsync(out, stage, (size_t)NB * NS * CO * 4, hipMemcpyDeviceToDevice,
                   stream);
  }
}

// Round 4
// 190.006 us; speedup vs baseline: 4.7159x; 1.0523x over previous
//
#include <hip/hip_runtime.h>
#include <math.h>

// Problem dims (fixed by the reference)
constexpr int NB  = 16;    // batch
constexpr int NP  = 1024;  // prev points
constexpr int NS  = 4096;  // skip points
constexpr int CP  = 256;   // prev channels
constexpr int CS  = 128;   // skip channels
constexpr int CIN = 384;   // CP + CS
constexpr int CO  = 256;   // output channels

constexpr int NCHUNK = 8;           // prev-point chunks for topk parallelism
constexpr int CHPTS  = NP / NCHUNK; // 128

typedef unsigned int uint;
typedef unsigned short ushort_t;
typedef __attribute__((ext_vector_type(8))) short short8;
typedef __attribute__((ext_vector_type(4))) float f32x4;

__device__ __forceinline__ ushort_t f2bf(float f) {
  uint u = __float_as_uint(f);
  uint r = (u + 0x7fffu + ((u >> 16) & 1u)) >> 16;   // RNE
  return (ushort_t)r;
}
__device__ __forceinline__ float bf2f(ushort_t u) {
  return __uint_as_float(((uint)u) << 16);
}

__device__ __forceinline__ void gload16(const void* g, void* l) {
  __builtin_amdgcn_global_load_lds(
      (const __attribute__((address_space(1))) uint*)g,
      (__attribute__((address_space(3))) uint*)l, 16, 0, 0);
}

// ---------------------------------------------------------------------------
// topk stage 1: per (skip point, chunk) partial top-3 (eps-shifted squared
// dists) + partial sum of reciprocal distances. Branchless insert, raw
// v_rsq_f32 (1e-6 rel err, weights tolerate), eps folded into the fma chain.
__global__ __launch_bounds__(256) void topk_chunk_kernel(
    const float* __restrict__ xyz_prev, const float* __restrict__ xyz_skip,
    float* __restrict__ pbuf) {
  __shared__ float px[CHPTS], py[CHPTS], pz[CHPTS];
  int ng = blockIdx.x;
  int q  = blockIdx.y;
  int b  = blockIdx.z;
  int tid = threadIdx.x;
  if (tid < CHPTS) {
    const float* xp = xyz_prev + ((size_t)b * NP + q * CHPTS + tid) * 3;
    px[tid] = xp[0]; py[tid] = xp[1]; pz[tid] = xp[2];
  }
  __syncthreads();
  int n = ng * 256 + tid;
  const float* xq = xyz_skip + ((size_t)b * NS + n) * 3;
  float qx = xq[0], qy = xq[1], qz = xq[2];
  float d0 = INFINITY, d1 = INFINITY, d2 = INFINITY;
  int i0 = -1, i1 = -1, i2 = -1;
  float rsum = 0.f;
  int pbase = q * CHPTS;

  #define TK_BODY(PX, PY, PZ, PI)                                        \
    {                                                                    \
      float dx = (PX) - qx, dy = (PY) - qy, dz = (PZ) - qz;              \
      float sq = fmaf(dz, dz, fmaf(dy, dy, fmaf(dx, dx, 1e-16f)));       \
      rsum += __builtin_amdgcn_rsqf(sq);                                 \
      bool c0 = sq < d0, c1 = sq < d1, c2 = sq < d2;                     \
      int pi = (PI);                                                     \
      d2 = c2 ? (c1 ? d1 : sq) : d2;                                     \
      i2 = c2 ? (c1 ? i1 : pi) : i2;                                     \
      d1 = c1 ? (c0 ? d0 : sq) : d1;                                     \
      i1 = c1 ? (c0 ? i0 : pi) : i1;                                     \
      d0 = c0 ? sq : d0;                                                 \
      i0 = c0 ? pi : i0;                                                 \
    }

  for (int p = 0; p < CHPTS; p += 4) {
    float4 X = *(const float4*)&px[p];
    float4 Y = *(const float4*)&py[p];
    float4 Z = *(const float4*)&pz[p];
    TK_BODY(X.x, Y.x, Z.x, pbase + p + 0);
    TK_BODY(X.y, Y.y, Z.y, pbase + p + 1);
    TK_BODY(X.z, Y.z, Z.z, pbase + p + 2);
    TK_BODY(X.w, Y.w, Z.w, pbase + p + 3);
  }
  #undef TK_BODY

  size_t P = ((size_t)(b * NCHUNK + q) * NS + n) * 8;
  float4 v0 = make_float4(d0, d1, d2, rsum);
  float4 v1;
  v1.x = __int_as_float(i0); v1.y = __int_as_float(i1);
  v1.z = __int_as_float(i2); v1.w = 0.f;
  *(float4*)(pbuf + P) = v0;
  *(float4*)(pbuf + P + 4) = v1;
}

// topk stage 2: merge NCHUNK partials per point, emit normalized 3-NN weights.
__global__ __launch_bounds__(256) void topk_merge_kernel(
    const float* __restrict__ pbuf, float* __restrict__ w3,
    int* __restrict__ idx3) {
  int gid = blockIdx.x * 256 + threadIdx.x;  // = b*NS + n
  int b = gid >> 12;
  int n = gid & (NS - 1);
  float d0 = INFINITY, d1 = INFINITY, d2 = INFINITY;
  int i0 = -1, i1 = -1, i2 = -1;
  float rsum = 0.f;
  for (int q = 0; q < NCHUNK; q++) {
    size_t P = ((size_t)(b * NCHUNK + q) * NS + n) * 8;
    float4 v0 = *(const float4*)(pbuf + P);
    float4 v1 = *(const float4*)(pbuf + P + 4);
    rsum += v0.w;
    float ds[3] = {v0.x, v0.y, v0.z};
    int   is[3] = {__float_as_int(v1.x), __float_as_int(v1.y),
                   __float_as_int(v1.z)};
    #pragma unroll
    for (int k = 0; k < 3; k++) {
      float sq = ds[k]; int pi = is[k];
      bool c0 = sq < d0, c1 = sq < d1, c2 = sq < d2;
      d2 = c2 ? (c1 ? d1 : sq) : d2;
      i2 = c2 ? (c1 ? i1 : pi) : i2;
      d1 = c1 ? (c0 ? d0 : sq) : d1;
      i1 = c1 ? (c0 ? i0 : pi) : i1;
      d0 = c0 ? sq : d0;
      i0 = c0 ? pi : i0;
    }
  }
  float inv = 1.0f / rsum;
  size_t base = (size_t)gid * 3;
  w3[base + 0] = __builtin_amdgcn_rsqf(d0) * inv;
  w3[base + 1] = __builtin_amdgcn_rsqf(d1) * inv;
  w3[base + 2] = __builtin_amdgcn_rsqf(d2) * inv;
  idx3[base + 0] = i0; idx3[base + 1] = i1; idx3[base + 2] = i2;
}

// ---------------------------------------------------------------------------
// W fp32 -> bf16 (both weight matrices), vectorized float4 -> ushort4.
__global__ __launch_bounds__(256) void wcast_kernel(
    const float* __restrict__ W1, const float* __restrict__ W2,
    ushort_t* __restrict__ W1b, ushort_t* __restrict__ W2b) {
  int t = blockIdx.x * 256 + threadIdx.x;
  int n1 = CO * CIN / 4;
  if (t < n1) {
    float4 v = *(const float4*)(W1 + t * 4);
    ushort4 o; o.x = f2bf(v.x); o.y = f2bf(v.y); o.z = f2bf(v.z); o.w = f2bf(v.w);
    *(ushort4*)(W1b + t * 4) = o;
  } else {
    int u = t - n1;
    float4 v = *(const float4*)(W2 + u * 4);
    ushort4 o; o.x = f2bf(v.x); o.y = f2bf(v.y); o.z = f2bf(v.z); o.w = f2bf(v.w);
    *(ushort4*)(W2b + u * 4) = o;
  }
}

// ---------------------------------------------------------------------------
// Transpose points_prev [b][256][1024] f32 -> pptT [b][1024][256] bf16.
__global__ __launch_bounds__(256) void ppT_kernel(
    const float* __restrict__ pp, ushort_t* __restrict__ pptT) {
  __shared__ float tl[64][65];
  int p0 = blockIdx.x * 64, c0 = blockIdx.y * 64, b = blockIdx.z;
  int tid = threadIdx.x;
  const float* P = pp + (size_t)b * CP * NP;
  int pi4 = (tid & 15) * 4, ci = tid >> 4;
  #pragma unroll
  for (int r = 0; r < 4; r++) {
    int cc = ci + 16 * r;
    float4 v = *(const float4*)(P + (size_t)(c0 + cc) * NP + p0 + pi4);
    tl[cc][pi4] = v.x; tl[cc][pi4 + 1] = v.y; tl[cc][pi4 + 2] = v.z; tl[cc][pi4 + 3] = v.w;
  }
  __syncthreads();
  ushort_t* O = pptT + (size_t)b * NP * CP;
  int ci4 = (tid & 15) * 4, pi = tid >> 4;
  #pragma unroll
  for (int r = 0; r < 4; r++) {
    int pr = pi + 16 * r;
    ushort4 o;
    o.x = f2bf(tl[ci4 + 0][pr]); o.y = f2bf(tl[ci4 + 1][pr]);
    o.z = f2bf(tl[ci4 + 2][pr]); o.w = f2bf(tl[ci4 + 3][pr]);
    *(ushort4*)(O + (size_t)(p0 + pr) * CP + c0 + ci4) = o;
  }
}

// Transpose points_skip [b][128][4096] f32 -> x1[b][n][256..383] bf16.
__global__ __launch_bounds__(256) void skipT_kernel(
    const float* __restrict__ sk, ushort_t* __restrict__ x1) {
  __shared__ float tl[64][65];
  int n0 = blockIdx.x * 64, c0 = blockIdx.y * 64, b = blockIdx.z;
  int tid = threadIdx.x;
  const float* S = sk + (size_t)b * CS * NS;
  int ni4 = (tid & 15) * 4, ci = tid >> 4;
  #pragma unroll
  for (int r = 0; r < 4; r++) {
    int cc = ci + 16 * r;
    float4 v = *(const float4*)(S + (size_t)(c0 + cc) * NS + n0 + ni4);
    tl[cc][ni4] = v.x; tl[cc][ni4 + 1] = v.y; tl[cc][ni4 + 2] = v.z; tl[cc][ni4 + 3] = v.w;
  }
  __syncthreads();
  ushort_t* O = x1 + (size_t)b * NS * CIN;
  int ci4 = (tid & 15) * 4, ni = tid >> 4;
  #pragma unroll
  for (int r = 0; r < 4; r++) {
    int nr = ni + 16 * r;
    ushort4 o;
    o.x = f2bf(tl[ci4 + 0][nr]); o.y = f2bf(tl[ci4 + 1][nr]);
    o.z = f2bf(tl[ci4 + 2][nr]); o.w = f2bf(tl[ci4 + 3][nr]);
    *(ushort4*)(O + (size_t)(n0 + nr) * CIN + CP + c0 + ci4) = o;
  }
}

// Interp: x1[b][n][0..255] = sum_k w3[k] * pptT[idx[k]][c].
__global__ __launch_bounds__(256) void interp_kernel(
    const ushort_t* __restrict__ pptT, const float* __restrict__ w3,
    const int* __restrict__ idx3, ushort_t* __restrict__ x1) {
  int tid = threadIdx.x;
  int nl = tid >> 6, l = tid & 63;
  int b = blockIdx.y;
  int n = blockIdx.x * 4 + nl;
  size_t nb = (size_t)b * NS + n;
  int j0 = idx3[nb * 3 + 0], j1 = idx3[nb * 3 + 1], j2 = idx3[nb * 3 + 2];
  float w0 = w3[nb * 3 + 0], w1 = w3[nb * 3 + 1], w2 = w3[nb * 3 + 2];
  const ushort_t* P = pptT + (size_t)b * NP * CP;
  int c = l * 4;
  ushort4 g0 = *(const ushort4*)(P + (size_t)j0 * CP + c);
  ushort4 g1 = *(const ushort4*)(P + (size_t)j1 * CP + c);
  ushort4 g2 = *(const ushort4*)(P + (size_t)j2 * CP + c);
  ushort4 o;
  o.x = f2bf(w0 * bf2f(g0.x) + w1 * bf2f(g1.x) + w2 * bf2f(g2.x));
  o.y = f2bf(w0 * bf2f(g0.y) + w1 * bf2f(g1.y) + w2 * bf2f(g2.y));
  o.z = f2bf(w0 * bf2f(g0.z) + w1 * bf2f(g1.z) + w2 * bf2f(g2.z));
  o.w = f2bf(w0 * bf2f(g0.w) + w1 * bf2f(g1.w) + w2 * bf2f(g2.w));
  *(ushort4*)(x1 + nb * CIN + c) = o;
}

// ---------------------------------------------------------------------------
// MFMA GEMM: D[b][n][o] = X[b][n][:] . Wb[o][:]  (K = KD), bf16 in, fp32 acc.
// 128x128 tile, 4 waves, 4x4 frags of 16x16x32. Writes bf16 or fp32 + stats.
template <int KD, bool OUT_BF16>
__global__ __launch_bounds__(256) void gemm_mfma_kernel(
    const ushort_t* __restrict__ X, const ushort_t* __restrict__ Wb,
    ushort_t* __restrict__ Yb, float* __restrict__ Yf,
    float* __restrict__ stats) {
  __shared__ ushort_t ldsX[128 * 32];
  __shared__ ushort_t ldsW[128 * 32];
  __shared__ float ssum[128], ssq[128];
  int tid = threadIdx.x;
  int w = tid >> 6, l = tid & 63;
  int n0 = blockIdx.x * 128;
  int by = blockIdx.y;
  int bz = blockIdx.z;
  if (tid < 128) { ssum[tid] = 0.f; ssq[tid] = 0.f; }

  f32x4 acc[4][4];
  #pragma unroll
  for (int i = 0; i < 4; i++)
    #pragma unroll
    for (int j = 0; j < 4; j++) acc[i][j] = {0.f, 0.f, 0.f, 0.f};

  int wn = (w & 1) * 64, wo = (w >> 1) * 64;
  int lr = l & 15, lk = l >> 4;
  const ushort_t* Xb = X + (size_t)bz * NS * KD;

  for (int kt = 0; kt < KD / 32; kt++) {
    int k0 = kt * 32;
    #pragma unroll
    for (int q = 0; q < 2; q++) {
      int r = q * 64 + w * 16 + (l >> 2);
      int cl = l & 3;
      int ks = k0 + 8 * (cl ^ ((r >> 1) & 3));
      gload16(Xb + (size_t)(n0 + r) * KD + ks, &ldsX[(q * 64 + w * 16) * 32]);
      gload16(Wb + (size_t)(by * 128 + r) * KD + ks, &ldsW[(q * 64 + w * 16) * 32]);
    }
    __syncthreads();
    short8 a[4], bfr[4];
    #pragma unroll
    for (int i = 0; i < 4; i++) {
      int rr = wn + i * 16 + lr;
      int cs = lk ^ ((rr >> 1) & 3);
      a[i] = *(const short8*)&ldsX[rr * 32 + cs * 8];
    }
    #pragma unroll
    for (int j = 0; j < 4; j++) {
      int rr = wo + j * 16 + lr;
      int cs = lk ^ ((rr >> 1) & 3);
      bfr[j] = *(const short8*)&ldsW[rr * 32 + cs * 8];
    }
    #pragma unroll
    for (int i = 0; i < 4; i++)
      #pragma unroll
      for (int j = 0; j < 4; j++)
        acc[i][j] = __builtin_amdgcn_mfma_f32_16x16x32_bf16(a[i], bfr[j], acc[i][j], 0, 0, 0);
    __syncthreads();
  }

  #pragma unroll
  for (int j = 0; j < 4; j++) {
    int ol = wo + j * 16 + lr;
    int og = by * 128 + ol;
    float ps = 0.f, pq = 0.f;
    #pragma unroll
    for (int i = 0; i < 4; i++) {
      #pragma unroll
      for (int rg = 0; rg < 4; rg++) {
        float v = acc[i][j][rg];
        ps += v; pq += v * v;
        int n = n0 + wn + i * 16 + lk * 4 + rg;
        size_t off = ((size_t)bz * NS + n) * CO + og;
        if (OUT_BF16) Yb[off] = f2bf(v);
        else Yf[off] = v;
      }
    }
    atomicAdd(&ssum[ol], ps);
    atomicAdd(&ssq[ol], pq);
  }
  __syncthreads();
  if (tid < 128) {
    atomicAdd(&stats[by * 128 + tid], ssum[tid]);
    atomicAdd(&stats[CO + by * 128 + tid], ssq[tid]);
  }
}

// stats -> per-channel affine
__global__ void bnstats_kernel(const float* __restrict__ stats,
                               const float* __restrict__ g,
                               const float* __restrict__ bt,
                               float* __restrict__ a, float* __restrict__ s) {
  int o = threadIdx.x;
  float cnt = (float)NB * (float)NS;
  float m = stats[o] / cnt;
  float var = stats[CO + o] / cnt - m * m;
  var = fmaxf(var, 0.f);
  float inv = rsqrtf(var + 1e-5f);
  float av = g[o] * inv;
  a[o] = av; s[o] = bt[o] - m * av;
}

// In-place BN+ReLU on y1b [b][n][256] bf16
__global__ __launch_bounds__(256) void act_kernel(
    ushort_t* __restrict__ y, const float* __restrict__ a,
    const float* __restrict__ s) {
  size_t i = ((size_t)blockIdx.x * 256 + threadIdx.x) * 8;
  int o = (int)(i & (CO - 1));
  ushort4 v0 = *(ushort4*)(y + i), v1 = *(ushort4*)(y + i + 4);
  ushort4 r0, r1;
  r0.x = f2bf(fmaxf(fmaf(a[o + 0], bf2f(v0.x), s[o + 0]), 0.f));
  r0.y = f2bf(fmaxf(fmaf(a[o + 1], bf2f(v0.y), s[o + 1]), 0.f));
  r0.z = f2bf(fmaxf(fmaf(a[o + 2], bf2f(v0.z), s[o + 2]), 0.f));
  r0.w = f2bf(fmaxf(fmaf(a[o + 3], bf2f(v0.w), s[o + 3]), 0.f));
  r1.x = f2bf(fmaxf(fmaf(a[o + 4], bf2f(v1.x), s[o + 4]), 0.f));
  r1.y = f2bf(fmaxf(fmaf(a[o + 5], bf2f(v1.y), s[o + 5]), 0.f));
  r1.z = f2bf(fmaxf(fmaf(a[o + 6], bf2f(v1.z), s[o + 6]), 0.f));
  r1.w = f2bf(fmaxf(fmaf(a[o + 7], bf2f(v1.w), s[o + 7]), 0.f));
  *(ushort4*)(y + i) = r0;
  *(ushort4*)(y + i + 4) = r1;
}

// Final BN2+ReLU with transpose, bf16 in [b][n][o] -> f32 out [b][o][n].
__global__ __launch_bounds__(256) void bnrelu_tr_kernel(
    const ushort_t* __restrict__ y2b, const float* __restrict__ a2,
    const float* __restrict__ s2, float* __restrict__ out) {
  __shared__ float tl[64][65];
  int n0 = blockIdx.x * 64, o0 = blockIdx.y * 64, b = blockIdx.z;
  const ushort_t* Y = y2b + (size_t)b * NS * CO;
  int tid = threadIdx.x;
  int o8 = (tid & 7) * 8, row = tid >> 3;     // 32 rows per pass, 2 passes
  #pragma unroll
  for (int r = 0; r < 2; r++) {
    int ii = row + 32 * r;
    const ushort_t* src = Y + (size_t)(n0 + ii) * CO + o0 + o8;
    ushort4 v0 = *(const ushort4*)(src);
    ushort4 v1 = *(const ushort4*)(src + 4);
    tl[ii][o8 + 0] = bf2f(v0.x); tl[ii][o8 + 1] = bf2f(v0.y);
    tl[ii][o8 + 2] = bf2f(v0.z); tl[ii][o8 + 3] = bf2f(v0.w);
    tl[ii][o8 + 4] = bf2f(v1.x); tl[ii][o8 + 5] = bf2f(v1.y);
    tl[ii][o8 + 6] = bf2f(v1.z); tl[ii][o8 + 7] = bf2f(v1.w);
  }
  __syncthreads();
  float* O = out + (size_t)b * CO * NS;
  int ii4 = (tid & 15) * 4, j = tid >> 4;
  #pragma unroll
  for (int r = 0; r < 4; r++) {
    int jj = j + 16 * r;
    float av = a2[o0 + jj], sv = s2[o0 + jj];
    float4 v;
    v.x = fmaxf(fmaf(av, tl[ii4 + 0][jj], sv), 0.f);
    v.y = fmaxf(fmaf(av, tl[ii4 + 1][jj], sv), 0.f);
    v.z = fmaxf(fmaf(av, tl[ii4 + 2][jj], sv), 0.f);
    v.w = fmaxf(fmaf(av, tl[ii4 + 3][jj], sv), 0.f);
    *(float4*)(O + (size_t)(o0 + jj) * NS + n0 + ii4) = v;
  }
}

__global__ void zero_kernel(float* st1, float* st2) {
  int t = threadIdx.x;
  if (t < 512) { st1[t] = 0.f; st2[t] = 0.f; }
}

extern "C" void kernel_launch(void* const* d_in, const int* in_sizes, int n_in,
                              void* d_out, int out_size, void* d_ws, size_t ws_size,
                              hipStream_t stream) {
  const float* xyz_prev    = (const float*)d_in[0];
  const float* xyz_skip    = (const float*)d_in[1];
  const float* points_prev = (const float*)d_in[2];
  const float* points_skip = (const float*)d_in[3];
  const float* W1 = (const float*)d_in[4];
  const float* g1 = (const float*)d_in[5];
  const float* b1 = (const float*)d_in[6];
  const float* W2 = (const float*)d_in[7];
  const float* g2 = (const float*)d_in[8];
  const float* b2 = (const float*)d_in[9];
  float* out = (float*)d_out;

  // workspace layout (256B-aligned sequential allocs)
  char* W = (char*)d_ws;
  size_t off = 0;
  auto alloc = [&](size_t bytes) {
    size_t o = off; off = (off + bytes + 255) & ~(size_t)255; return o;
  };
  ushort_t* x1   = (ushort_t*)(W + alloc((size_t)NB * NS * CIN * 2));  // 50.3MB
  ushort_t* y1b  = (ushort_t*)(W + alloc((size_t)NB * NS * CO * 2));   // 33.6MB
  ushort_t* pptT = (ushort_t*)(W + alloc((size_t)NB * NP * CP * 2));   // 8.4MB
  ushort_t* W1b  = (ushort_t*)(W + alloc((size_t)CO * CIN * 2));
  ushort_t* W2b  = (ushort_t*)(W + alloc((size_t)CO * CO * 2));
  float* w3   = (float*)(W + alloc((size_t)NB * NS * 3 * 4));
  int*   idx3 = (int*)(W + alloc((size_t)NB * NS * 3 * 4));
  float* st1  = (float*)(W + alloc(512 * 4));
  float* st2  = (float*)(W + alloc(512 * 4));
  float* ab   = (float*)(W + alloc(1024 * 4));
  float* a1 = ab, *s1 = ab + 256, *a2 = ab + 512, *s2 = ab + 768;
  size_t y2_off = alloc((size_t)NB * NS * CO * 2);                     // 33.6MB bf16
  bool full = (ws_size >= off);
  // y2 bf16: in ws if it fits, else in d_out (bf16 33.6MB < 67MB out buffer)
  ushort_t* y2b = full ? (ushort_t*)(W + y2_off) : (ushort_t*)d_out;
  // pbuf (16.8MB, transient, consumed before any y2 write) aliases y2 region
  float* pbuf = full ? (float*)(W + y2_off) : (float*)d_out;

  hipLaunchKernelGGL(zero_kernel, dim3(1), dim3(512), 0, stream, st1, st2);
  hipLaunchKernelGGL(topk_chunk_kernel, dim3(NS / 256, NCHUNK, NB), dim3(256), 0,
                     stream, xyz_prev, xyz_skip, pbuf);
  hipLaunchKernelGGL(topk_merge_kernel, dim3(NB * NS / 256), dim3(256), 0, stream,
                     pbuf, w3, idx3);
  hipLaunchKernelGGL(wcast_kernel, dim3((CO * CIN / 4 + CO * CO / 4 + 255) / 256),
                     dim3(256), 0, stream, W1, W2, W1b, W2b);
  hipLaunchKernelGGL(ppT_kernel, dim3(NP / 64, CP / 64, NB), dim3(256), 0, stream,
                     points_prev, pptT);
  hipLaunchKernelGGL(skipT_kernel, dim3(NS / 64, CS / 64, NB), dim3(256), 0, stream,
                     points_skip, x1);
  hipLaunchKernelGGL(interp_kernel, dim3(NS / 4, NB), dim3(256), 0, stream,
                     pptT, w3, idx3, x1);
  hipLaunchKernelGGL((gemm_mfma_kernel<CIN, true>), dim3(NS / 128, 2, NB), dim3(256),
                     0, stream, x1, W1b, y1b, (float*)nullptr, st1);
  hipLaunchKernelGGL(bnstats_kernel, dim3(1), dim3(256), 0, stream, st1, g1, b1, a1, s1);
  hipLaunchKernelGGL(act_kernel, dim3((int)((size_t)NB * NS * CO / 8 / 256)),
                     dim3(256), 0, stream, y1b, a1, s1);
  hipLaunchKernelGGL((gemm_mfma_kernel<CO, true>), dim3(NS / 128, 2, NB), dim3(256),
                     0, stream, y1b, W2b, y2b, (float*)nullptr, st2);
  hipLaunchKernelGGL(bnstats_kernel, dim3(1), dim3(256), 0, stream, st2, g2, b2, a2, s2);
  if (full) {
    hipLaunchKernelGGL(bnrelu_tr_kernel, dim3(NS / 64, CO / 64, NB), dim3(256), 0,
                       stream, y2b, a2, s2, out);
  } else {
    // y2b lives in d_out: stage final f32 into ws (x1+y1b region, dead), copy back
    float* stage = (float*)d_ws;
    hipLaunchKernelGGL(bnrelu_tr_kernel, dim3(NS / 64, CO / 64, NB), dim3(256), 0,
                       stream, y2b, a2, s2, stage);
    hipMemcpyAsync(out, stage, (size_t)NB * NS * CO * 4, hipMemcpyDeviceToDevice,
                   stream);
  }
}

// Round 5
// 176.653 us; speedup vs baseline: 5.0724x; 1.0756x over previous
//
#include <hip/hip_runtime.h>
#include <math.h>

// Problem dims (fixed by the reference)
constexpr int NB  = 16;    // batch
constexpr int NP  = 1024;  // prev points
constexpr int NS  = 4096;  // skip points
constexpr int CP  = 256;   // prev channels
constexpr int CS  = 128;   // skip channels
constexpr int CIN = 384;   // CP + CS
constexpr int CO  = 256;   // output channels

constexpr int NCHUNK = 8;           // prev-point chunks for topk parallelism
constexpr int CHPTS  = NP / NCHUNK; // 128

typedef unsigned int uint;
typedef unsigned short ushort_t;
typedef __attribute__((ext_vector_type(8))) short short8;
typedef __attribute__((ext_vector_type(4))) float f32x4;

__device__ __forceinline__ ushort_t f2bf(float f) {
  uint u = __float_as_uint(f);
  uint r = (u + 0x7fffu + ((u >> 16) & 1u)) >> 16;   // RNE
  return (ushort_t)r;
}
__device__ __forceinline__ float bf2f(ushort_t u) {
  return __uint_as_float(((uint)u) << 16);
}
__device__ __forceinline__ uint pk2(ushort_t lo, ushort_t hi) {
  return (uint)lo | ((uint)hi << 16);
}

__device__ __forceinline__ void gload16(const void* g, void* l) {
  __builtin_amdgcn_global_load_lds(
      (const __attribute__((address_space(1))) uint*)g,
      (__attribute__((address_space(3))) uint*)l, 16, 0, 0);
}

// Branchless top-3 step: values via min/med3, indices via cndmask.
__device__ __forceinline__ void tk_step(float pxv, float pyv, float pzv, int pi,
                                        float qx, float qy, float qz,
                                        float& d0, float& d1, float& d2,
                                        int& i0, int& i1, int& i2, float& rsum) {
  float dx = pxv - qx, dy = pyv - qy, dz = pzv - qz;
  float sq = fmaf(dz, dz, fmaf(dy, dy, fmaf(dx, dx, 1e-16f)));
  rsum += __builtin_amdgcn_rsqf(sq);
  bool c0 = sq < d0, c1 = sq < d1, c2 = sq < d2;
  i2 = c2 ? (c1 ? i1 : pi) : i2;
  i1 = c1 ? (c0 ? i0 : pi) : i1;
  i0 = c0 ? pi : i0;
  d2 = __builtin_amdgcn_fmed3f(d1, d2, sq);
  d1 = __builtin_amdgcn_fmed3f(d0, d1, sq);
  d0 = fminf(d0, sq);
}

// ---------------------------------------------------------------------------
// topk stage 1: 2 queries per thread (doubles ILP on the selection chain,
// halves LDS reads per pair). grid (NS/512, NCHUNK, NB), block 256.
__global__ __launch_bounds__(256) void topk_chunk_kernel(
    const float* __restrict__ xyz_prev, const float* __restrict__ xyz_skip,
    float* __restrict__ pbuf) {
  __shared__ float px[CHPTS], py[CHPTS], pz[CHPTS];
  int q  = blockIdx.y;
  int b  = blockIdx.z;
  int tid = threadIdx.x;
  if (tid < CHPTS) {
    const float* xp = xyz_prev + ((size_t)b * NP + q * CHPTS + tid) * 3;
    px[tid] = xp[0]; py[tid] = xp[1]; pz[tid] = xp[2];
  }
  __syncthreads();
  int nA = blockIdx.x * 512 + tid;
  int nB = nA + 256;
  const float* xqA = xyz_skip + ((size_t)b * NS + nA) * 3;
  const float* xqB = xyz_skip + ((size_t)b * NS + nB) * 3;
  float qxA = xqA[0], qyA = xqA[1], qzA = xqA[2];
  float qxB = xqB[0], qyB = xqB[1], qzB = xqB[2];
  float dA0 = INFINITY, dA1 = INFINITY, dA2 = INFINITY;
  float dB0 = INFINITY, dB1 = INFINITY, dB2 = INFINITY;
  int iA0 = -1, iA1 = -1, iA2 = -1, iB0 = -1, iB1 = -1, iB2 = -1;
  float rsA = 0.f, rsB = 0.f;
  int pbase = q * CHPTS;

  for (int p = 0; p < CHPTS; p += 4) {
    float4 X = *(const float4*)&px[p];
    float4 Y = *(const float4*)&py[p];
    float4 Z = *(const float4*)&pz[p];
    tk_step(X.x, Y.x, Z.x, pbase + p + 0, qxA, qyA, qzA, dA0, dA1, dA2, iA0, iA1, iA2, rsA);
    tk_step(X.x, Y.x, Z.x, pbase + p + 0, qxB, qyB, qzB, dB0, dB1, dB2, iB0, iB1, iB2, rsB);
    tk_step(X.y, Y.y, Z.y, pbase + p + 1, qxA, qyA, qzA, dA0, dA1, dA2, iA0, iA1, iA2, rsA);
    tk_step(X.y, Y.y, Z.y, pbase + p + 1, qxB, qyB, qzB, dB0, dB1, dB2, iB0, iB1, iB2, rsB);
    tk_step(X.z, Y.z, Z.z, pbase + p + 2, qxA, qyA, qzA, dA0, dA1, dA2, iA0, iA1, iA2, rsA);
    tk_step(X.z, Y.z, Z.z, pbase + p + 2, qxB, qyB, qzB, dB0, dB1, dB2, iB0, iB1, iB2, rsB);
    tk_step(X.w, Y.w, Z.w, pbase + p + 3, qxA, qyA, qzA, dA0, dA1, dA2, iA0, iA1, iA2, rsA);
    tk_step(X.w, Y.w, Z.w, pbase + p + 3, qxB, qyB, qzB, dB0, dB1, dB2, iB0, iB1, iB2, rsB);
  }

  size_t PA = ((size_t)(b * NCHUNK + q) * NS + nA) * 8;
  size_t PB = ((size_t)(b * NCHUNK + q) * NS + nB) * 8;
  float4 a0 = make_float4(dA0, dA1, dA2, rsA);
  float4 a1; a1.x = __int_as_float(iA0); a1.y = __int_as_float(iA1);
  a1.z = __int_as_float(iA2); a1.w = 0.f;
  float4 b0 = make_float4(dB0, dB1, dB2, rsB);
  float4 b1; b1.x = __int_as_float(iB0); b1.y = __int_as_float(iB1);
  b1.z = __int_as_float(iB2); b1.w = 0.f;
  *(float4*)(pbuf + PA) = a0;
  *(float4*)(pbuf + PA + 4) = a1;
  *(float4*)(pbuf + PB) = b0;
  *(float4*)(pbuf + PB + 4) = b1;
}

// topk stage 2: merge NCHUNK partials per point, emit normalized 3-NN weights.
__global__ __launch_bounds__(256) void topk_merge_kernel(
    const float* __restrict__ pbuf, float* __restrict__ w3,
    int* __restrict__ idx3) {
  int gid = blockIdx.x * 256 + threadIdx.x;  // = b*NS + n
  int b = gid >> 12;
  int n = gid & (NS - 1);
  float d0 = INFINITY, d1 = INFINITY, d2 = INFINITY;
  int i0 = -1, i1 = -1, i2 = -1;
  float rsum = 0.f;
  for (int q = 0; q < NCHUNK; q++) {
    size_t P = ((size_t)(b * NCHUNK + q) * NS + n) * 8;
    float4 v0 = *(const float4*)(pbuf + P);
    float4 v1 = *(const float4*)(pbuf + P + 4);
    rsum += v0.w;
    float ds[3] = {v0.x, v0.y, v0.z};
    int   is[3] = {__float_as_int(v1.x), __float_as_int(v1.y),
                   __float_as_int(v1.z)};
    #pragma unroll
    for (int k = 0; k < 3; k++) {
      float sq = ds[k]; int pi = is[k];
      bool c0 = sq < d0, c1 = sq < d1, c2 = sq < d2;
      i2 = c2 ? (c1 ? i1 : pi) : i2;
      i1 = c1 ? (c0 ? i0 : pi) : i1;
      i0 = c0 ? pi : i0;
      d2 = __builtin_amdgcn_fmed3f(d1, d2, sq);
      d1 = __builtin_amdgcn_fmed3f(d0, d1, sq);
      d0 = fminf(d0, sq);
    }
  }
  float inv = 1.0f / rsum;
  size_t base = (size_t)gid * 3;
  w3[base + 0] = __builtin_amdgcn_rsqf(d0) * inv;
  w3[base + 1] = __builtin_amdgcn_rsqf(d1) * inv;
  w3[base + 2] = __builtin_amdgcn_rsqf(d2) * inv;
  idx3[base + 0] = i0; idx3[base + 1] = i1; idx3[base + 2] = i2;
}

// ---------------------------------------------------------------------------
// W fp32 -> bf16 (both weight matrices); block 0 also zeros the BN stats.
__global__ __launch_bounds__(256) void wcast_kernel(
    const float* __restrict__ W1, const float* __restrict__ W2,
    ushort_t* __restrict__ W1b, ushort_t* __restrict__ W2b,
    float* __restrict__ st1, float* __restrict__ st2) {
  int tid = threadIdx.x;
  if (blockIdx.x == 0) {
    st1[tid] = 0.f; st1[tid + 256] = 0.f;
    st2[tid] = 0.f; st2[tid + 256] = 0.f;
  }
  int t = blockIdx.x * 256 + tid;
  int n1 = CO * CIN / 4;
  if (t < n1) {
    float4 v = *(const float4*)(W1 + t * 4);
    ushort4 o; o.x = f2bf(v.x); o.y = f2bf(v.y); o.z = f2bf(v.z); o.w = f2bf(v.w);
    *(ushort4*)(W1b + t * 4) = o;
  } else {
    int u = t - n1;
    float4 v = *(const float4*)(W2 + u * 4);
    ushort4 o; o.x = f2bf(v.x); o.y = f2bf(v.y); o.z = f2bf(v.z); o.w = f2bf(v.w);
    *(ushort4*)(W2b + u * 4) = o;
  }
}

// ---------------------------------------------------------------------------
// Transpose points_prev [b][256][1024] f32 -> pptT [b][1024][256] bf16.
__global__ __launch_bounds__(256) void ppT_kernel(
    const float* __restrict__ pp, ushort_t* __restrict__ pptT) {
  __shared__ float tl[64][65];
  int p0 = blockIdx.x * 64, c0 = blockIdx.y * 64, b = blockIdx.z;
  int tid = threadIdx.x;
  const float* P = pp + (size_t)b * CP * NP;
  int pi4 = (tid & 15) * 4, ci = tid >> 4;
  #pragma unroll
  for (int r = 0; r < 4; r++) {
    int cc = ci + 16 * r;
    float4 v = *(const float4*)(P + (size_t)(c0 + cc) * NP + p0 + pi4);
    tl[cc][pi4] = v.x; tl[cc][pi4 + 1] = v.y; tl[cc][pi4 + 2] = v.z; tl[cc][pi4 + 3] = v.w;
  }
  __syncthreads();
  ushort_t* O = pptT + (size_t)b * NP * CP;
  int ci4 = (tid & 15) * 4, pi = tid >> 4;
  #pragma unroll
  for (int r = 0; r < 4; r++) {
    int pr = pi + 16 * r;
    ushort4 o;
    o.x = f2bf(tl[ci4 + 0][pr]); o.y = f2bf(tl[ci4 + 1][pr]);
    o.z = f2bf(tl[ci4 + 2][pr]); o.w = f2bf(tl[ci4 + 3][pr]);
    *(ushort4*)(O + (size_t)(p0 + pr) * CP + c0 + ci4) = o;
  }
}

// Transpose points_skip [b][128][4096] f32 -> x1[b][n][256..383] bf16.
__global__ __launch_bounds__(256) void skipT_kernel(
    const float* __restrict__ sk, ushort_t* __restrict__ x1) {
  __shared__ float tl[64][65];
  int n0 = blockIdx.x * 64, c0 = blockIdx.y * 64, b = blockIdx.z;
  int tid = threadIdx.x;
  const float* S = sk + (size_t)b * CS * NS;
  int ni4 = (tid & 15) * 4, ci = tid >> 4;
  #pragma unroll
  for (int r = 0; r < 4; r++) {
    int cc = ci + 16 * r;
    float4 v = *(const float4*)(S + (size_t)(c0 + cc) * NS + n0 + ni4);
    tl[cc][ni4] = v.x; tl[cc][ni4 + 1] = v.y; tl[cc][ni4 + 2] = v.z; tl[cc][ni4 + 3] = v.w;
  }
  __syncthreads();
  ushort_t* O = x1 + (size_t)b * NS * CIN;
  int ci4 = (tid & 15) * 4, ni = tid >> 4;
  #pragma unroll
  for (int r = 0; r < 4; r++) {
    int nr = ni + 16 * r;
    ushort4 o;
    o.x = f2bf(tl[ci4 + 0][nr]); o.y = f2bf(tl[ci4 + 1][nr]);
    o.z = f2bf(tl[ci4 + 2][nr]); o.w = f2bf(tl[ci4 + 3][nr]);
    *(ushort4*)(O + (size_t)(n0 + nr) * CIN + CP + c0 + ci4) = o;
  }
}

// Interp: x1[b][n][0..255] = sum_k w3[k] * pptT[idx[k]][c].
__global__ __launch_bounds__(256) void interp_kernel(
    const ushort_t* __restrict__ pptT, const float* __restrict__ w3,
    const int* __restrict__ idx3, ushort_t* __restrict__ x1) {
  int tid = threadIdx.x;
  int nl = tid >> 6, l = tid & 63;
  int b = blockIdx.y;
  int n = blockIdx.x * 4 + nl;
  size_t nb = (size_t)b * NS + n;
  int j0 = idx3[nb * 3 + 0], j1 = idx3[nb * 3 + 1], j2 = idx3[nb * 3 + 2];
  float w0 = w3[nb * 3 + 0], w1 = w3[nb * 3 + 1], w2 = w3[nb * 3 + 2];
  const ushort_t* P = pptT + (size_t)b * NP * CP;
  int c = l * 4;
  ushort4 g0 = *(const ushort4*)(P + (size_t)j0 * CP + c);
  ushort4 g1 = *(const ushort4*)(P + (size_t)j1 * CP + c);
  ushort4 g2 = *(const ushort4*)(P + (size_t)j2 * CP + c);
  ushort4 o;
  o.x = f2bf(w0 * bf2f(g0.x) + w1 * bf2f(g1.x) + w2 * bf2f(g2.x));
  o.y = f2bf(w0 * bf2f(g0.y) + w1 * bf2f(g1.y) + w2 * bf2f(g2.y));
  o.z = f2bf(w0 * bf2f(g0.z) + w1 * bf2f(g1.z) + w2 * bf2f(g2.z));
  o.w = f2bf(w0 * bf2f(g0.w) + w1 * bf2f(g1.w) + w2 * bf2f(g2.w));
  *(ushort4*)(x1 + nb * CIN + c) = o;
}

// ---------------------------------------------------------------------------
// MFMA GEMM: D[b][n][o] = X[b][n][:] . Wb[o][:]  (K = KD), bf16 in, fp32 acc.
// 128x128 tile, 4 waves, 4x4 frags of 16x16x32. ACT: apply y=relu(aa*x+ss)
// to X during reg-staging (used by gemm2 to fold in BN1+ReLU).
template <int KD, bool ACT>
__global__ __launch_bounds__(256) void gemm_mfma_kernel(
    const ushort_t* __restrict__ X, const ushort_t* __restrict__ Wb,
    const float* __restrict__ aa, const float* __restrict__ ss,
    ushort_t* __restrict__ Yb, float* __restrict__ stats) {
  __shared__ ushort_t ldsX[128 * 32];
  __shared__ ushort_t ldsW[128 * 32];
  __shared__ float ssum[128], ssq[128];
  int tid = threadIdx.x;
  int w = tid >> 6, l = tid & 63;
  int n0 = blockIdx.x * 128;
  int by = blockIdx.y;
  int bz = blockIdx.z;
  if (tid < 128) { ssum[tid] = 0.f; ssq[tid] = 0.f; }

  f32x4 acc[4][4];
  #pragma unroll
  for (int i = 0; i < 4; i++)
    #pragma unroll
    for (int j = 0; j < 4; j++) acc[i][j] = {0.f, 0.f, 0.f, 0.f};

  int wn = (w & 1) * 64, wo = (w >> 1) * 64;
  int lr = l & 15, lk = l >> 4;
  const ushort_t* Xb = X + (size_t)bz * NS * KD;
  int rbase = w * 16 + (l >> 2);
  int cl = l & 3;
  int ksw = 8 * (cl ^ ((rbase >> 1) & 3));   // swizzled k-offset (q-invariant)

  for (int kt = 0; kt < KD / 32; kt++) {
    int k0 = kt * 32;
    int ks = k0 + ksw;
    // W tile: async global->LDS
    #pragma unroll
    for (int q = 0; q < 2; q++) {
      int r = q * 64 + rbase;
      gload16(Wb + (size_t)(by * 128 + r) * KD + ks, &ldsW[(q * 64 + w * 16) * 32]);
    }
    // X tile
    if constexpr (!ACT) {
      #pragma unroll
      for (int q = 0; q < 2; q++) {
        int r = q * 64 + rbase;
        gload16(Xb + (size_t)(n0 + r) * KD + ks, &ldsX[(q * 64 + w * 16) * 32]);
      }
    } else {
      float4 av0 = *(const float4*)(aa + ks);
      float4 av1 = *(const float4*)(aa + ks + 4);
      float4 sv0 = *(const float4*)(ss + ks);
      float4 sv1 = *(const float4*)(ss + ks + 4);
      #pragma unroll
      for (int q = 0; q < 2; q++) {
        int r = q * 64 + rbase;
        const ushort_t* src = Xb + (size_t)(n0 + r) * KD + ks;
        ushort4 v0 = *(const ushort4*)(src);
        ushort4 v1 = *(const ushort4*)(src + 4);
        int4 o;
        o.x = (int)pk2(f2bf(fmaxf(fmaf(av0.x, bf2f(v0.x), sv0.x), 0.f)),
                       f2bf(fmaxf(fmaf(av0.y, bf2f(v0.y), sv0.y), 0.f)));
        o.y = (int)pk2(f2bf(fmaxf(fmaf(av0.z, bf2f(v0.z), sv0.z), 0.f)),
                       f2bf(fmaxf(fmaf(av0.w, bf2f(v0.w), sv0.w), 0.f)));
        o.z = (int)pk2(f2bf(fmaxf(fmaf(av1.x, bf2f(v1.x), sv1.x), 0.f)),
                       f2bf(fmaxf(fmaf(av1.y, bf2f(v1.y), sv1.y), 0.f)));
        o.w = (int)pk2(f2bf(fmaxf(fmaf(av1.z, bf2f(v1.z), sv1.z), 0.f)),
                       f2bf(fmaxf(fmaf(av1.w, bf2f(v1.w), sv1.w), 0.f)));
        *(int4*)&ldsX[(q * 64 + w * 16) * 32 + l * 8] = o;
      }
    }
    __syncthreads();
    short8 a[4], bfr[4];
    #pragma unroll
    for (int i = 0; i < 4; i++) {
      int rr = wn + i * 16 + lr;
      int cs = lk ^ ((rr >> 1) & 3);
      a[i] = *(const short8*)&ldsX[rr * 32 + cs * 8];
    }
    #pragma unroll
    for (int j = 0; j < 4; j++) {
      int rr = wo + j * 16 + lr;
      int cs = lk ^ ((rr >> 1) & 3);
      bfr[j] = *(const short8*)&ldsW[rr * 32 + cs * 8];
    }
    #pragma unroll
    for (int i = 0; i < 4; i++)
      #pragma unroll
      for (int j = 0; j < 4; j++)
        acc[i][j] = __builtin_amdgcn_mfma_f32_16x16x32_bf16(a[i], bfr[j], acc[i][j], 0, 0, 0);
    __syncthreads();
  }

  #pragma unroll
  for (int j = 0; j < 4; j++) {
    int ol = wo + j * 16 + lr;
    int og = by * 128 + ol;
    float ps = 0.f, pq = 0.f;
    #pragma unroll
    for (int i = 0; i < 4; i++) {
      #pragma unroll
      for (int rg = 0; rg < 4; rg++) {
        float v = acc[i][j][rg];
        ps += v; pq += v * v;
        int n = n0 + wn + i * 16 + lk * 4 + rg;
        Yb[((size_t)bz * NS + n) * CO + og] = f2bf(v);
      }
    }
    atomicAdd(&ssum[ol], ps);
    atomicAdd(&ssq[ol], pq);
  }
  __syncthreads();
  if (tid < 128) {
    atomicAdd(&stats[by * 128 + tid], ssum[tid]);
    atomicAdd(&stats[CO + by * 128 + tid], ssq[tid]);
  }
}

// stats -> per-channel affine
__global__ void bnstats_kernel(const float* __restrict__ stats,
                               const float* __restrict__ g,
                               const float* __restrict__ bt,
                               float* __restrict__ a, float* __restrict__ s) {
  int o = threadIdx.x;
  float cnt = (float)NB * (float)NS;
  float m = stats[o] / cnt;
  float var = stats[CO + o] / cnt - m * m;
  var = fmaxf(var, 0.f);
  float inv = rsqrtf(var + 1e-5f);
  float av = g[o] * inv;
  a[o] = av; s[o] = bt[o] - m * av;
}

// Final BN2+ReLU with transpose, bf16 in [b][n][o] -> f32 out [b][o][n].
__global__ __launch_bounds__(256) void bnrelu_tr_kernel(
    const ushort_t* __restrict__ y2b, const float* __restrict__ a2,
    const float* __restrict__ s2, float* __restrict__ out) {
  __shared__ float tl[64][65];
  int n0 = blockIdx.x * 64, o0 = blockIdx.y * 64, b = blockIdx.z;
  const ushort_t* Y = y2b + (size_t)b * NS * CO;
  int tid = threadIdx.x;
  int o8 = (tid & 7) * 8, row = tid >> 3;
  #pragma unroll
  for (int r = 0; r < 2; r++) {
    int ii = row + 32 * r;
    const ushort_t* src = Y + (size_t)(n0 + ii) * CO + o0 + o8;
    ushort4 v0 = *(const ushort4*)(src);
    ushort4 v1 = *(const ushort4*)(src + 4);
    tl[ii][o8 + 0] = bf2f(v0.x); tl[ii][o8 + 1] = bf2f(v0.y);
    tl[ii][o8 + 2] = bf2f(v0.z); tl[ii][o8 + 3] = bf2f(v0.w);
    tl[ii][o8 + 4] = bf2f(v1.x); tl[ii][o8 + 5] = bf2f(v1.y);
    tl[ii][o8 + 6] = bf2f(v1.z); tl[ii][o8 + 7] = bf2f(v1.w);
  }
  __syncthreads();
  float* O = out + (size_t)b * CO * NS;
  int ii4 = (tid & 15) * 4, j = tid >> 4;
  #pragma unroll
  for (int r = 0; r < 4; r++) {
    int jj = j + 16 * r;
    float av = a2[o0 + jj], sv = s2[o0 + jj];
    float4 v;
    v.x = fmaxf(fmaf(av, tl[ii4 + 0][jj], sv), 0.f);
    v.y = fmaxf(fmaf(av, tl[ii4 + 1][jj], sv), 0.f);
    v.z = fmaxf(fmaf(av, tl[ii4 + 2][jj], sv), 0.f);
    v.w = fmaxf(fmaf(av, tl[ii4 + 3][jj], sv), 0.f);
    *(float4*)(O + (size_t)(o0 + jj) * NS + n0 + ii4) = v;
  }
}

extern "C" void kernel_launch(void* const* d_in, const int* in_sizes, int n_in,
                              void* d_out, int out_size, void* d_ws, size_t ws_size,
                              hipStream_t stream) {
  const float* xyz_prev    = (const float*)d_in[0];
  const float* xyz_skip    = (const float*)d_in[1];
  const float* points_prev = (const float*)d_in[2];
  const float* points_skip = (const float*)d_in[3];
  const float* W1 = (const float*)d_in[4];
  const float* g1 = (const float*)d_in[5];
  const float* b1 = (const float*)d_in[6];
  const float* W2 = (const float*)d_in[7];
  const float* g2 = (const float*)d_in[8];
  const float* b2 = (const float*)d_in[9];
  float* out = (float*)d_out;

  // workspace layout (256B-aligned sequential allocs)
  char* W = (char*)d_ws;
  size_t off = 0;
  auto alloc = [&](size_t bytes) {
    size_t o = off; off = (off + bytes + 255) & ~(size_t)255; return o;
  };
  ushort_t* x1   = (ushort_t*)(W + alloc((size_t)NB * NS * CIN * 2));  // 50.3MB
  ushort_t* y1b  = (ushort_t*)(W + alloc((size_t)NB * NS * CO * 2));   // 33.6MB
  ushort_t* pptT = (ushort_t*)(W + alloc((size_t)NB * NP * CP * 2));   // 8.4MB
  ushort_t* W1b  = (ushort_t*)(W + alloc((size_t)CO * CIN * 2));
  ushort_t* W2b  = (ushort_t*)(W + alloc((size_t)CO * CO * 2));
  float* w3   = (float*)(W + alloc((size_t)NB * NS * 3 * 4));
  int*   idx3 = (int*)(W + alloc((size_t)NB * NS * 3 * 4));
  float* st1  = (float*)(W + alloc(512 * 4));
  float* st2  = (float*)(W + alloc(512 * 4));
  float* ab   = (float*)(W + alloc(1024 * 4));
  float* a1 = ab, *s1 = ab + 256, *a2 = ab + 512, *s2 = ab + 768;
  size_t y2_off = alloc((size_t)NB * NS * CO * 2);                     // 33.6MB bf16
  bool full = (ws_size >= off);
  // y2 bf16: in ws if it fits, else in d_out (bf16 33.6MB < 67MB out buffer)
  ushort_t* y2b = full ? (ushort_t*)(W + y2_off) : (ushort_t*)d_out;
  // pbuf (16.8MB, transient, consumed before any y2 write) aliases y2 region
  float* pbuf = full ? (float*)(W + y2_off) : (float*)d_out;

  hipLaunchKernelGGL(topk_chunk_kernel, dim3(NS / 512, NCHUNK, NB), dim3(256), 0,
                     stream, xyz_prev, xyz_skip, pbuf);
  hipLaunchKernelGGL(topk_merge_kernel, dim3(NB * NS / 256), dim3(256), 0, stream,
                     pbuf, w3, idx3);
  hipLaunchKernelGGL(wcast_kernel, dim3((CO * CIN / 4 + CO * CO / 4 + 255) / 256),
                     dim3(256), 0, stream, W1, W2, W1b, W2b, st1, st2);
  hipLaunchKernelGGL(ppT_kernel, dim3(NP / 64, CP / 64, NB), dim3(256), 0, stream,
                     points_prev, pptT);
  hipLaunchKernelGGL(skipT_kernel, dim3(NS / 64, CS / 64, NB), dim3(256), 0, stream,
                     points_skip, x1);
  hipLaunchKernelGGL(interp_kernel, dim3(NS / 4, NB), dim3(256), 0, stream,
                     pptT, w3, idx3, x1);
  hipLaunchKernelGGL((gemm_mfma_kernel<CIN, false>), dim3(NS / 128, 2, NB), dim3(256),
                     0, stream, x1, W1b, (const float*)nullptr, (const float*)nullptr,
                     y1b, st1);
  hipLaunchKernelGGL(bnstats_kernel, dim3(1), dim3(256), 0, stream, st1, g1, b1, a1, s1);
  hipLaunchKernelGGL((gemm_mfma_kernel<CO, true>), dim3(NS / 128, 2, NB), dim3(256),
                     0, stream, y1b, W2b, a1, s1, y2b, st2);
  hipLaunchKernelGGL(bnstats_kernel, dim3(1), dim3(256), 0, stream, st2, g2, b2, a2, s2);
  if (full) {
    hipLaunchKernelGGL(bnrelu_tr_kernel, dim3(NS / 64, CO / 64, NB), dim3(256), 0,
                       stream, y2b, a2, s2, out);
  } else {
    // y2b lives in d_out: stage final f32 into ws (x1+y1b region, dead), copy back
    float* stage = (float*)d_ws;
    hipLaunchKernelGGL(bnrelu_tr_kernel, dim3(NS / 64, CO / 64, NB), dim3(256), 0,
                       stream, y2b, a2, s2, stage);
    hipMemcpyAsync(out, stage, (size_t)NB * NS * CO * 4, hipMemcpyDeviceToDevice,
                   stream);
  }
}

// Round 6
// 157.857 us; speedup vs baseline: 5.6763x; 1.1191x over previous
//
#include <hip/hip_runtime.h>
#include <math.h>

// Problem dims (fixed by the reference)
constexpr int NB  = 16;    // batch
constexpr int NP  = 1024;  // prev points
constexpr int NS  = 4096;  // skip points
constexpr int CP  = 256;   // prev channels
constexpr int CS  = 128;   // skip channels
constexpr int CIN = 384;   // CP + CS
constexpr int CO  = 256;   // output channels

constexpr int NCHUNK = 16;          // prev-point chunks for topk parallelism
constexpr int CHPTS  = NP / NCHUNK; // 64

typedef unsigned int uint;
typedef unsigned short ushort_t;
typedef __attribute__((ext_vector_type(8))) short short8;
typedef __attribute__((ext_vector_type(4))) float f32x4;

__device__ __forceinline__ ushort_t f2bf(float f) {
  uint u = __float_as_uint(f);
  uint r = (u + 0x7fffu + ((u >> 16) & 1u)) >> 16;   // RNE
  return (ushort_t)r;
}
__device__ __forceinline__ float bf2f(ushort_t u) {
  return __uint_as_float(((uint)u) << 16);
}
__device__ __forceinline__ uint pk2(ushort_t lo, ushort_t hi) {
  return (uint)lo | ((uint)hi << 16);
}

__device__ __forceinline__ void gload16(const void* g, void* l) {
  __builtin_amdgcn_global_load_lds(
      (const __attribute__((address_space(1))) uint*)g,
      (__attribute__((address_space(3))) uint*)l, 16, 0, 0);
}

// Packed-key top-3 step. key = (bits(sq) & ~1023) | idx — positive floats
// order like uints, so fmin/fmed3 track BOTH distance and index. Lower idx
// wins ties (matches jax top_k). Masked-dist error <= 2^-13 relative; a
// rank-3/4 set-swap costs ~0.01 in the output (weights normalize over all
// 1024 points) — far under the 0.107 threshold.
__device__ __forceinline__ void tkp(float pxv, float pyv, float pzv, int pi,
                                    float qx, float qy, float qz,
                                    float& k0, float& k1, float& k2,
                                    float& rsum) {
  float dx = pxv - qx, dy = pyv - qy, dz = pzv - qz;
  float sq = fmaf(dz, dz, fmaf(dy, dy, fmaf(dx, dx, 1e-16f)));
  rsum += __builtin_amdgcn_rsqf(sq);
  float k = __uint_as_float((__float_as_uint(sq) & 0xFFFFFC00u) | (uint)pi);
  k2 = __builtin_amdgcn_fmed3f(k1, k2, k);
  k1 = __builtin_amdgcn_fmed3f(k0, k1, k);
  k0 = fminf(k0, k);
}

// ---------------------------------------------------------------------------
// topk stage 1: per (skip point, chunk) partial top-3 packed keys + partial
// reciprocal-distance sum. 2 queries/thread. grid (NS/512, NCHUNK, NB).
__global__ __launch_bounds__(256) void topk_chunk_kernel(
    const float* __restrict__ xyz_prev, const float* __restrict__ xyz_skip,
    float* __restrict__ pbuf) {
  __shared__ float px[CHPTS], py[CHPTS], pz[CHPTS];
  int q  = blockIdx.y;
  int b  = blockIdx.z;
  int tid = threadIdx.x;
  if (tid < CHPTS) {
    const float* xp = xyz_prev + ((size_t)b * NP + q * CHPTS + tid) * 3;
    px[tid] = xp[0]; py[tid] = xp[1]; pz[tid] = xp[2];
  }
  __syncthreads();
  int nA = blockIdx.x * 512 + tid;
  int nB = nA + 256;
  const float* xqA = xyz_skip + ((size_t)b * NS + nA) * 3;
  const float* xqB = xyz_skip + ((size_t)b * NS + nB) * 3;
  float qxA = xqA[0], qyA = xqA[1], qzA = xqA[2];
  float qxB = xqB[0], qyB = xqB[1], qzB = xqB[2];
  float kA0 = INFINITY, kA1 = INFINITY, kA2 = INFINITY;
  float kB0 = INFINITY, kB1 = INFINITY, kB2 = INFINITY;
  float rsA = 0.f, rsB = 0.f;
  int pbase = q * CHPTS;

  for (int p = 0; p < CHPTS; p += 4) {
    float4 X = *(const float4*)&px[p];
    float4 Y = *(const float4*)&py[p];
    float4 Z = *(const float4*)&pz[p];
    tkp(X.x, Y.x, Z.x, pbase + p + 0, qxA, qyA, qzA, kA0, kA1, kA2, rsA);
    tkp(X.x, Y.x, Z.x, pbase + p + 0, qxB, qyB, qzB, kB0, kB1, kB2, rsB);
    tkp(X.y, Y.y, Z.y, pbase + p + 1, qxA, qyA, qzA, kA0, kA1, kA2, rsA);
    tkp(X.y, Y.y, Z.y, pbase + p + 1, qxB, qyB, qzB, kB0, kB1, kB2, rsB);
    tkp(X.z, Y.z, Z.z, pbase + p + 2, qxA, qyA, qzA, kA0, kA1, kA2, rsA);
    tkp(X.z, Y.z, Z.z, pbase + p + 2, qxB, qyB, qzB, kB0, kB1, kB2, rsB);
    tkp(X.w, Y.w, Z.w, pbase + p + 3, qxA, qyA, qzA, kA0, kA1, kA2, rsA);
    tkp(X.w, Y.w, Z.w, pbase + p + 3, qxB, qyB, qzB, kB0, kB1, kB2, rsB);
  }

  size_t PA = ((size_t)(b * NCHUNK + q) * NS + nA) * 4;
  size_t PB = ((size_t)(b * NCHUNK + q) * NS + nB) * 4;
  *(float4*)(pbuf + PA) = make_float4(kA0, kA1, kA2, rsA);
  *(float4*)(pbuf + PB) = make_float4(kB0, kB1, kB2, rsB);
}

// topk stage 2: merge NCHUNK packed partials, emit normalized 3-NN weights.
__global__ __launch_bounds__(256) void topk_merge_kernel(
    const float* __restrict__ pbuf, float* __restrict__ w3,
    int* __restrict__ idx3) {
  int gid = blockIdx.x * 256 + threadIdx.x;  // = b*NS + n
  int b = gid >> 12;
  int n = gid & (NS - 1);
  float k0 = INFINITY, k1 = INFINITY, k2 = INFINITY;
  float rsum = 0.f;
  #pragma unroll 4
  for (int q = 0; q < NCHUNK; q++) {
    float4 v = *(const float4*)(pbuf + ((size_t)(b * NCHUNK + q) * NS + n) * 4);
    rsum += v.w;
    k2 = __builtin_amdgcn_fmed3f(k1, k2, v.x);
    k1 = __builtin_amdgcn_fmed3f(k0, k1, v.x);
    k0 = fminf(k0, v.x);
    k2 = __builtin_amdgcn_fmed3f(k1, k2, v.y);
    k1 = __builtin_amdgcn_fmed3f(k0, k1, v.y);
    k0 = fminf(k0, v.y);
    k2 = __builtin_amdgcn_fmed3f(k1, k2, v.z);
    k1 = __builtin_amdgcn_fmed3f(k0, k1, v.z);
    k0 = fminf(k0, v.z);
  }
  float inv = 1.0f / rsum;
  uint u0 = __float_as_uint(k0), u1 = __float_as_uint(k1), u2 = __float_as_uint(k2);
  float d0 = __uint_as_float(u0 & 0xFFFFFC00u);
  float d1 = __uint_as_float(u1 & 0xFFFFFC00u);
  float d2 = __uint_as_float(u2 & 0xFFFFFC00u);
  size_t base = (size_t)gid * 3;
  w3[base + 0] = __builtin_amdgcn_rsqf(d0) * inv;
  w3[base + 1] = __builtin_amdgcn_rsqf(d1) * inv;
  w3[base + 2] = __builtin_amdgcn_rsqf(d2) * inv;
  idx3[base + 0] = (int)(u0 & 1023u);
  idx3[base + 1] = (int)(u1 & 1023u);
  idx3[base + 2] = (int)(u2 & 1023u);
}

// ---------------------------------------------------------------------------
// W fp32 -> bf16 (both weight matrices); block 0 also zeros the BN stats.
__global__ __launch_bounds__(256) void wcast_kernel(
    const float* __restrict__ W1, const float* __restrict__ W2,
    ushort_t* __restrict__ W1b, ushort_t* __restrict__ W2b,
    float* __restrict__ st1, float* __restrict__ st2) {
  int tid = threadIdx.x;
  if (blockIdx.x == 0) {
    st1[tid] = 0.f; st1[tid + 256] = 0.f;
    st2[tid] = 0.f; st2[tid + 256] = 0.f;
  }
  int t = blockIdx.x * 256 + tid;
  int n1 = CO * CIN / 4;
  if (t < n1) {
    float4 v = *(const float4*)(W1 + t * 4);
    ushort4 o; o.x = f2bf(v.x); o.y = f2bf(v.y); o.z = f2bf(v.z); o.w = f2bf(v.w);
    *(ushort4*)(W1b + t * 4) = o;
  } else {
    int u = t - n1;
    float4 v = *(const float4*)(W2 + u * 4);
    ushort4 o; o.x = f2bf(v.x); o.y = f2bf(v.y); o.z = f2bf(v.z); o.w = f2bf(v.w);
    *(ushort4*)(W2b + u * 4) = o;
  }
}

// ---------------------------------------------------------------------------
// Transpose points_prev [b][256][1024] f32 -> pptT [b][1024][256] bf16.
__global__ __launch_bounds__(256) void ppT_kernel(
    const float* __restrict__ pp, ushort_t* __restrict__ pptT) {
  __shared__ float tl[64][65];
  int p0 = blockIdx.x * 64, c0 = blockIdx.y * 64, b = blockIdx.z;
  int tid = threadIdx.x;
  const float* P = pp + (size_t)b * CP * NP;
  int pi4 = (tid & 15) * 4, ci = tid >> 4;
  #pragma unroll
  for (int r = 0; r < 4; r++) {
    int cc = ci + 16 * r;
    float4 v = *(const float4*)(P + (size_t)(c0 + cc) * NP + p0 + pi4);
    tl[cc][pi4] = v.x; tl[cc][pi4 + 1] = v.y; tl[cc][pi4 + 2] = v.z; tl[cc][pi4 + 3] = v.w;
  }
  __syncthreads();
  ushort_t* O = pptT + (size_t)b * NP * CP;
  int ci4 = (tid & 15) * 4, pi = tid >> 4;
  #pragma unroll
  for (int r = 0; r < 4; r++) {
    int pr = pi + 16 * r;
    ushort4 o;
    o.x = f2bf(tl[ci4 + 0][pr]); o.y = f2bf(tl[ci4 + 1][pr]);
    o.z = f2bf(tl[ci4 + 2][pr]); o.w = f2bf(tl[ci4 + 3][pr]);
    *(ushort4*)(O + (size_t)(p0 + pr) * CP + c0 + ci4) = o;
  }
}

// Transpose points_skip [b][128][4096] f32 -> x1[b][n][256..383] bf16.
__global__ __launch_bounds__(256) void skipT_kernel(
    const float* __restrict__ sk, ushort_t* __restrict__ x1) {
  __shared__ float tl[64][65];
  int n0 = blockIdx.x * 64, c0 = blockIdx.y * 64, b = blockIdx.z;
  int tid = threadIdx.x;
  const float* S = sk + (size_t)b * CS * NS;
  int ni4 = (tid & 15) * 4, ci = tid >> 4;
  #pragma unroll
  for (int r = 0; r < 4; r++) {
    int cc = ci + 16 * r;
    float4 v = *(const float4*)(S + (size_t)(c0 + cc) * NS + n0 + ni4);
    tl[cc][ni4] = v.x; tl[cc][ni4 + 1] = v.y; tl[cc][ni4 + 2] = v.z; tl[cc][ni4 + 3] = v.w;
  }
  __syncthreads();
  ushort_t* O = x1 + (size_t)b * NS * CIN;
  int ci4 = (tid & 15) * 4, ni = tid >> 4;
  #pragma unroll
  for (int r = 0; r < 4; r++) {
    int nr = ni + 16 * r;
    ushort4 o;
    o.x = f2bf(tl[ci4 + 0][nr]); o.y = f2bf(tl[ci4 + 1][nr]);
    o.z = f2bf(tl[ci4 + 2][nr]); o.w = f2bf(tl[ci4 + 3][nr]);
    *(ushort4*)(O + (size_t)(n0 + nr) * CIN + CP + c0 + ci4) = o;
  }
}

// Interp: x1[b][n][0..255] = sum_k w3[k] * pptT[idx[k]][c].
__global__ __launch_bounds__(256) void interp_kernel(
    const ushort_t* __restrict__ pptT, const float* __restrict__ w3,
    const int* __restrict__ idx3, ushort_t* __restrict__ x1) {
  int tid = threadIdx.x;
  int nl = tid >> 6, l = tid & 63;
  int b = blockIdx.y;
  int n = blockIdx.x * 4 + nl;
  size_t nb = (size_t)b * NS + n;
  int j0 = idx3[nb * 3 + 0], j1 = idx3[nb * 3 + 1], j2 = idx3[nb * 3 + 2];
  float w0 = w3[nb * 3 + 0], w1 = w3[nb * 3 + 1], w2 = w3[nb * 3 + 2];
  const ushort_t* P = pptT + (size_t)b * NP * CP;
  int c = l * 4;
  ushort4 g0 = *(const ushort4*)(P + (size_t)j0 * CP + c);
  ushort4 g1 = *(const ushort4*)(P + (size_t)j1 * CP + c);
  ushort4 g2 = *(const ushort4*)(P + (size_t)j2 * CP + c);
  ushort4 o;
  o.x = f2bf(w0 * bf2f(g0.x) + w1 * bf2f(g1.x) + w2 * bf2f(g2.x));
  o.y = f2bf(w0 * bf2f(g0.y) + w1 * bf2f(g1.y) + w2 * bf2f(g2.y));
  o.z = f2bf(w0 * bf2f(g0.z) + w1 * bf2f(g1.z) + w2 * bf2f(g2.z));
  o.w = f2bf(w0 * bf2f(g0.w) + w1 * bf2f(g1.w) + w2 * bf2f(g2.w));
  *(ushort4*)(x1 + nb * CIN + c) = o;
}

// ---------------------------------------------------------------------------
// MFMA GEMM: D[b][n][o] = X[b][n][:] . Wb[o][:]  (K = KD), bf16 in, fp32 acc.
// 128x128 tile, 4 waves, 4x4 frags of 16x16x32. ACT: computes the BN1 affine
// from stats in the prologue and applies y=relu(a*x+s) to X while reg-staging.
// Grid is 1D=1024 with a mod-8-preserving decode so the two by-blocks sharing
// an X panel land on the SAME XCD (second read hits that XCD's L2).
template <int KD, bool ACT>
__global__ __launch_bounds__(256) void gemm_mfma_kernel(
    const ushort_t* __restrict__ X, const ushort_t* __restrict__ Wb,
    const float* __restrict__ stats_in, const float* __restrict__ g_in,
    const float* __restrict__ bt_in,
    ushort_t* __restrict__ Yb, float* __restrict__ stats) {
  __shared__ ushort_t ldsX[128 * 32];
  __shared__ ushort_t ldsW[128 * 32];
  __shared__ float ssum[128], ssq[128];
  __shared__ float a1s[ACT ? CO : 1], s1s[ACT ? CO : 1];
  int tid = threadIdx.x;
  int w = tid >> 6, l = tid & 63;
  int bid = blockIdx.x;
  int by = (bid >> 3) & 1;
  int s  = (bid & 7) + 8 * (bid >> 4);
  int bx = s & 31;
  int bz = s >> 5;
  int n0 = bx * 128;
  if (tid < 128) { ssum[tid] = 0.f; ssq[tid] = 0.f; }
  if constexpr (ACT) {
    float cnt = (float)NB * (float)NS;
    float m = stats_in[tid] / cnt;
    float var = stats_in[CO + tid] / cnt - m * m;
    var = fmaxf(var, 0.f);
    float invs = rsqrtf(var + 1e-5f);
    float av = g_in[tid] * invs;
    a1s[tid] = av; s1s[tid] = bt_in[tid] - m * av;
  }
  __syncthreads();

  f32x4 acc[4][4];
  #pragma unroll
  for (int i = 0; i < 4; i++)
    #pragma unroll
    for (int j = 0; j < 4; j++) acc[i][j] = {0.f, 0.f, 0.f, 0.f};

  int wn = (w & 1) * 64, wo = (w >> 1) * 64;
  int lr = l & 15, lk = l >> 4;
  const ushort_t* Xb = X + (size_t)bz * NS * KD;
  int rbase = w * 16 + (l >> 2);
  int cl = l & 3;
  int ksw = 8 * (cl ^ ((rbase >> 1) & 3));   // swizzled k-offset (q-invariant)

  for (int kt = 0; kt < KD / 32; kt++) {
    int k0 = kt * 32;
    int ks = k0 + ksw;
    #pragma unroll
    for (int q = 0; q < 2; q++) {
      int r = q * 64 + rbase;
      gload16(Wb + (size_t)(by * 128 + r) * KD + ks, &ldsW[(q * 64 + w * 16) * 32]);
    }
    if constexpr (!ACT) {
      #pragma unroll
      for (int q = 0; q < 2; q++) {
        int r = q * 64 + rbase;
        gload16(Xb + (size_t)(n0 + r) * KD + ks, &ldsX[(q * 64 + w * 16) * 32]);
      }
    } else {
      float4 av0 = *(const float4*)&a1s[ks];
      float4 av1 = *(const float4*)&a1s[ks + 4];
      float4 sv0 = *(const float4*)&s1s[ks];
      float4 sv1 = *(const float4*)&s1s[ks + 4];
      #pragma unroll
      for (int q = 0; q < 2; q++) {
        int r = q * 64 + rbase;
        const ushort_t* src = Xb + (size_t)(n0 + r) * KD + ks;
        ushort4 v0 = *(const ushort4*)(src);
        ushort4 v1 = *(const ushort4*)(src + 4);
        int4 o;
        o.x = (int)pk2(f2bf(fmaxf(fmaf(av0.x, bf2f(v0.x), sv0.x), 0.f)),
                       f2bf(fmaxf(fmaf(av0.y, bf2f(v0.y), sv0.y), 0.f)));
        o.y = (int)pk2(f2bf(fmaxf(fmaf(av0.z, bf2f(v0.z), sv0.z), 0.f)),
                       f2bf(fmaxf(fmaf(av0.w, bf2f(v0.w), sv0.w), 0.f)));
        o.z = (int)pk2(f2bf(fmaxf(fmaf(av1.x, bf2f(v1.x), sv1.x), 0.f)),
                       f2bf(fmaxf(fmaf(av1.y, bf2f(v1.y), sv1.y), 0.f)));
        o.w = (int)pk2(f2bf(fmaxf(fmaf(av1.z, bf2f(v1.z), sv1.z), 0.f)),
                       f2bf(fmaxf(fmaf(av1.w, bf2f(v1.w), sv1.w), 0.f)));
        *(int4*)&ldsX[(q * 64 + w * 16) * 32 + l * 8] = o;
      }
    }
    __syncthreads();
    short8 a[4], bfr[4];
    #pragma unroll
    for (int i = 0; i < 4; i++) {
      int rr = wn + i * 16 + lr;
      int cs = lk ^ ((rr >> 1) & 3);
      a[i] = *(const short8*)&ldsX[rr * 32 + cs * 8];
    }
    #pragma unroll
    for (int j = 0; j < 4; j++) {
      int rr = wo + j * 16 + lr;
      int cs = lk ^ ((rr >> 1) & 3);
      bfr[j] = *(const short8*)&ldsW[rr * 32 + cs * 8];
    }
    #pragma unroll
    for (int i = 0; i < 4; i++)
      #pragma unroll
      for (int j = 0; j < 4; j++)
        acc[i][j] = __builtin_amdgcn_mfma_f32_16x16x32_bf16(a[i], bfr[j], acc[i][j], 0, 0, 0);
    __syncthreads();
  }

  #pragma unroll
  for (int j = 0; j < 4; j++) {
    int ol = wo + j * 16 + lr;
    int og = by * 128 + ol;
    float ps = 0.f, pq = 0.f;
    #pragma unroll
    for (int i = 0; i < 4; i++) {
      #pragma unroll
      for (int rg = 0; rg < 4; rg++) {
        float v = acc[i][j][rg];
        ps += v; pq += v * v;
        int n = n0 + wn + i * 16 + lk * 4 + rg;
        Yb[((size_t)bz * NS + n) * CO + og] = f2bf(v);
      }
    }
    atomicAdd(&ssum[ol], ps);
    atomicAdd(&ssq[ol], pq);
  }
  __syncthreads();
  if (tid < 128) {
    atomicAdd(&stats[by * 128 + tid], ssum[tid]);
    atomicAdd(&stats[CO + by * 128 + tid], ssq[tid]);
  }
}

// Final BN2+ReLU with transpose, bf16 in [b][n][o] -> f32 out [b][o][n].
// Computes the BN2 affine from stats in the prologue (bnstats folded in).
__global__ __launch_bounds__(256) void bnrelu_tr_kernel(
    const ushort_t* __restrict__ y2b, const float* __restrict__ stats_in,
    const float* __restrict__ g_in, const float* __restrict__ bt_in,
    float* __restrict__ out) {
  __shared__ float tl[64][65];
  __shared__ float a2s[64], s2s[64];
  int n0 = blockIdx.x * 64, o0 = blockIdx.y * 64, b = blockIdx.z;
  const ushort_t* Y = y2b + (size_t)b * NS * CO;
  int tid = threadIdx.x;
  if (tid < 64) {
    int o = o0 + tid;
    float cnt = (float)NB * (float)NS;
    float m = stats_in[o] / cnt;
    float var = stats_in[CO + o] / cnt - m * m;
    var = fmaxf(var, 0.f);
    float invs = rsqrtf(var + 1e-5f);
    float av = g_in[o] * invs;
    a2s[tid] = av; s2s[tid] = bt_in[o] - m * av;
  }
  int o8 = (tid & 7) * 8, row = tid >> 3;
  #pragma unroll
  for (int r = 0; r < 2; r++) {
    int ii = row + 32 * r;
    const ushort_t* src = Y + (size_t)(n0 + ii) * CO + o0 + o8;
    ushort4 v0 = *(const ushort4*)(src);
    ushort4 v1 = *(const ushort4*)(src + 4);
    tl[ii][o8 + 0] = bf2f(v0.x); tl[ii][o8 + 1] = bf2f(v0.y);
    tl[ii][o8 + 2] = bf2f(v0.z); tl[ii][o8 + 3] = bf2f(v0.w);
    tl[ii][o8 + 4] = bf2f(v1.x); tl[ii][o8 + 5] = bf2f(v1.y);
    tl[ii][o8 + 6] = bf2f(v1.z); tl[ii][o8 + 7] = bf2f(v1.w);
  }
  __syncthreads();
  float* O = out + (size_t)b * CO * NS;
  int ii4 = (tid & 15) * 4, j = tid >> 4;
  #pragma unroll
  for (int r = 0; r < 4; r++) {
    int jj = j + 16 * r;
    float av = a2s[jj], sv = s2s[jj];
    float4 v;
    v.x = fmaxf(fmaf(av, tl[ii4 + 0][jj], sv), 0.f);
    v.y = fmaxf(fmaf(av, tl[ii4 + 1][jj], sv), 0.f);
    v.z = fmaxf(fmaf(av, tl[ii4 + 2][jj], sv), 0.f);
    v.w = fmaxf(fmaf(av, tl[ii4 + 3][jj], sv), 0.f);
    *(float4*)(O + (size_t)(o0 + jj) * NS + n0 + ii4) = v;
  }
}

extern "C" void kernel_launch(void* const* d_in, const int* in_sizes, int n_in,
                              void* d_out, int out_size, void* d_ws, size_t ws_size,
                              hipStream_t stream) {
  const float* xyz_prev    = (const float*)d_in[0];
  const float* xyz_skip    = (const float*)d_in[1];
  const float* points_prev = (const float*)d_in[2];
  const float* points_skip = (const float*)d_in[3];
  const float* W1 = (const float*)d_in[4];
  const float* g1 = (const float*)d_in[5];
  const float* b1 = (const float*)d_in[6];
  const float* W2 = (const float*)d_in[7];
  const float* g2 = (const float*)d_in[8];
  const float* b2 = (const float*)d_in[9];
  float* out = (float*)d_out;

  // workspace layout (256B-aligned sequential allocs)
  char* W = (char*)d_ws;
  size_t off = 0;
  auto alloc = [&](size_t bytes) {
    size_t o = off; off = (off + bytes + 255) & ~(size_t)255; return o;
  };
  ushort_t* x1   = (ushort_t*)(W + alloc((size_t)NB * NS * CIN * 2));  // 50.3MB
  ushort_t* y1b  = (ushort_t*)(W + alloc((size_t)NB * NS * CO * 2));   // 33.6MB
  ushort_t* pptT = (ushort_t*)(W + alloc((size_t)NB * NP * CP * 2));   // 8.4MB
  ushort_t* W1b  = (ushort_t*)(W + alloc((size_t)CO * CIN * 2));
  ushort_t* W2b  = (ushort_t*)(W + alloc((size_t)CO * CO * 2));
  float* w3   = (float*)(W + alloc((size_t)NB * NS * 3 * 4));
  int*   idx3 = (int*)(W + alloc((size_t)NB * NS * 3 * 4));
  float* st1  = (float*)(W + alloc(512 * 4));
  float* st2  = (float*)(W + alloc(512 * 4));
  size_t y2_off = alloc((size_t)NB * NS * CO * 2);                     // 33.6MB bf16
  bool full = (ws_size >= off);
  // y2 bf16: in ws if it fits, else in d_out (bf16 33.6MB < 67MB out buffer)
  ushort_t* y2b = full ? (ushort_t*)(W + y2_off) : (ushort_t*)d_out;
  // pbuf (16.8MB, transient, consumed before any y2 write) aliases y2 region
  float* pbuf = full ? (float*)(W + y2_off) : (float*)d_out;

  hipLaunchKernelGGL(topk_chunk_kernel, dim3(NS / 512, NCHUNK, NB), dim3(256), 0,
                     stream, xyz_prev, xyz_skip, pbuf);
  hipLaunchKernelGGL(topk_merge_kernel, dim3(NB * NS / 256), dim3(256), 0, stream,
                     pbuf, w3, idx3);
  hipLaunchKernelGGL(wcast_kernel, dim3((CO * CIN / 4 + CO * CO / 4 + 255) / 256),
                     dim3(256), 0, stream, W1, W2, W1b, W2b, st1, st2);
  hipLaunchKernelGGL(ppT_kernel, dim3(NP / 64, CP / 64, NB), dim3(256), 0, stream,
                     points_prev, pptT);
  hipLaunchKernelGGL(skipT_kernel, dim3(NS / 64, CS / 64, NB), dim3(256), 0, stream,
                     points_skip, x1);
  hipLaunchKernelGGL(interp_kernel, dim3(NS / 4, NB), dim3(256), 0, stream,
                     pptT, w3, idx3, x1);
  hipLaunchKernelGGL((gemm_mfma_kernel<CIN, false>), dim3(1024), dim3(256),
                     0, stream, x1, W1b, (const float*)nullptr,
                     (const float*)nullptr, (const float*)nullptr, y1b, st1);
  hipLaunchKernelGGL((gemm_mfma_kernel<CO, true>), dim3(1024), dim3(256),
                     0, stream, y1b, W2b, st1, g1, b1, y2b, st2);
  if (full) {
    hipLaunchKernelGGL(bnrelu_tr_kernel, dim3(NS / 64, CO / 64, NB), dim3(256), 0,
                       stream, y2b, st2, g2, b2, out);
  } else {
    // y2b lives in d_out: stage final f32 into ws (x1+y1b region, dead), copy back
    float* stage = (float*)d_ws;
    hipLaunchKernelGGL(bnrelu_tr_kernel, dim3(NS / 64, CO / 64, NB), dim3(256), 0,
                       stream, y2b, st2, g2, b2, stage);
    hipMemcpyAsync(out, stage, (size_t)NB * NS * CO * 4, hipMemcpyDeviceToDevice,
                   stream);
  }
}